// Round 18
// baseline (77.419 us; speedup 1.0000x reference)
//
#include <hip/hip_runtime.h>

#define CC 192
#define LOG100 4.6051701859880914f
#define PSHIFT 11.0f   // softmax-invariant scale: keeps fp16 P out of subnormals
#define LOG2E  1.4426950408889634f

typedef _Float16 half8v __attribute__((ext_vector_type(8)));
typedef _Float16 half4v __attribute__((ext_vector_type(4)));
typedef float f32x4 __attribute__((ext_vector_type(4)));

static __device__ __forceinline__ f32x4 mfma_k32(half8v a, half8v b, f32x4 c) {
#if __has_builtin(__builtin_amdgcn_mfma_f32_16x16x32_f16)
  return __builtin_amdgcn_mfma_f32_16x16x32_f16(a, b, c, 0, 0, 0);
#else
  asm("v_mfma_f32_16x16x32_f16 %0, %1, %2, %0" : "+v"(c) : "v"(a), "v"(b));
  return c;
#endif
}
static __device__ __forceinline__ f32x4 mfma_k16(half4v a, half4v b, f32x4 c) {
#if __has_builtin(__builtin_amdgcn_mfma_f32_16x16x16f16)
  return __builtin_amdgcn_mfma_f32_16x16x16f16(a, b, c, 0, 0, 0);
#else
  asm("v_mfma_f32_16x16x16_f16 %0, %1, %2, %0" : "+v"(c) : "v"(a), "v"(b));
  return c;
#endif
}
static __device__ __forceinline__ float exp2fast(float x) {
#if __has_builtin(__builtin_amdgcn_exp2f)
  return __builtin_amdgcn_exp2f(x);
#else
  return exp2f(x);
#endif
}

// ---------------------------------------------------------------------------
// cvt_cpb: fused prepass.
//   Blocks [0,6912):     roll+window gather f32->fp16 (xh)
//   Blocks [6912,7153):  CPB MLP -> Rtab (4 entries/block, 1 per wave)
//   Blocks [7153,7297):  qkv_w + proj_w f32 -> fp16 (wh, ph)
// ---------------------------------------------------------------------------
__global__ __launch_bounds__(256) void cvt_cpb(
    const float* __restrict__ x, _Float16* __restrict__ xh,
    const float* __restrict__ tab, const float* __restrict__ w1,
    const float* __restrict__ b1, const float* __restrict__ w2,
    const float* __restrict__ ls, float* __restrict__ Rtab,
    const float* __restrict__ qkvw, const float* __restrict__ projw,
    _Float16* __restrict__ wh, _Float16* __restrict__ ph)
{
  if (blockIdx.x < 6912) {
    const int q = blockIdx.x * 256 + threadIdx.x;   // float4 units: 36864*48
    const int token = q / 48;
    const int c4 = q - token * 48;
    const int wb = token >> 8;
    const int n = token & 255;
    const int b = wb / 36;
    const int wq = wb - b * 36;
    const int wy = wq / 6;
    const int wx = wq - wy * 6;
    const int iy = (wy * 16 + (n >> 4) + 8) % 96;
    const int ix = (wx * 16 + (n & 15) + 8) % 96;
    const float4 v = *(const float4*)(x + (size_t)((b * 96 + iy) * 96 + ix) * CC + c4 * 4);
    half4v hv = {(_Float16)v.x, (_Float16)v.y, (_Float16)v.z, (_Float16)v.w};
    *(half4v*)(xh + (size_t)token * CC + c4 * 4) = hv;
    return;
  }
  if (blockIdx.x >= 7153) {
    const int q = (blockIdx.x - 7153) * 256 + threadIdx.x;  // 0..36863 float4 units
    float4 v;
    _Float16* dst;
    int off;
    if (q < 27648) { v = *(const float4*)(qkvw + q * 4); dst = wh; off = q * 4; }
    else { const int p2 = q - 27648; v = *(const float4*)(projw + p2 * 4); dst = ph; off = p2 * 4; }
    half4v hv = {(_Float16)v.x, (_Float16)v.y, (_Float16)v.z, (_Float16)v.w};
    *(half4v*)(dst + off) = hv;
    return;
  }
  const int p = (blockIdx.x - 6912) * 4 + (threadIdx.x >> 6);
  if (p >= 961) return;
  const int lane = threadIdx.x & 63;
  const float t0 = tab[p*2+0];
  const float t1 = tab[p*2+1];
  float a0=0.f,a1=0.f,a2=0.f,a3=0.f,a4=0.f,a5=0.f;
  for (int j = lane; j < 512; j += 64) {
    float hv = fmaxf(fmaf(t0, w1[2*j], fmaf(t1, w1[2*j+1], b1[j])), 0.f);
    a0 = fmaf(hv, w2[0*512+j], a0);
    a1 = fmaf(hv, w2[1*512+j], a1);
    a2 = fmaf(hv, w2[2*512+j], a2);
    a3 = fmaf(hv, w2[3*512+j], a3);
    a4 = fmaf(hv, w2[4*512+j], a4);
    a5 = fmaf(hv, w2[5*512+j], a5);
  }
  #pragma unroll
  for (int off = 32; off > 0; off >>= 1) {
    a0 += __shfl_down(a0, off);
    a1 += __shfl_down(a1, off);
    a2 += __shfl_down(a2, off);
    a3 += __shfl_down(a3, off);
    a4 += __shfl_down(a4, off);
    a5 += __shfl_down(a5, off);
  }
  if (lane == 0) {
    float av[6] = {a0, a1, a2, a3, a4, a5};
    #pragma unroll
    for (int h = 0; h < 6; h++) {
      const float rpb = 16.f / (1.f + __expf(-av[h]));
      const float bound = __expf(fminf(ls[h], LOG100)) + 16.f;
      Rtab[h*961 + p] = (rpb - bound + PSHIFT) * LOG2E;
    }
  }
}

// ---------------------------------------------------------------------------
// qkv_mfma: grid (576 token-tiles, 3 parts). x staged ONCE per block; loops
// over the part's 3 head-pair feature tiles (xh L3 re-reads 9x -> 3x).
// wsm doubles as epilogue scratch between barriers. LDS 49.2KB -> 3 blk/CU.
// ---------------------------------------------------------------------------
__global__ __launch_bounds__(256) void qkv_mfma(
    const _Float16* __restrict__ xh, const _Float16* __restrict__ wh,
    const float* __restrict__ q_bias, const float* __restrict__ v_bias,
    const float* __restrict__ ls,
    _Float16* __restrict__ qh, _Float16* __restrict__ kh,
    _Float16* __restrict__ vhT)
{
  __shared__ _Float16 xs[64*200];
  __shared__ _Float16 wsm[64*200];
  const int tid = threadIdx.x;
  const int tok0 = blockIdx.x * 64;
  const int part = blockIdx.y;          // 0=q 1=k 2=v (block-uniform)

  // ---- stage x tile once: contiguous fp16 copy ----
  {
    const _Float16* src = xh + (size_t)tok0 * CC;
    #pragma unroll
    for (int it = 0; it < 6; it++) {
      const int u = it*256 + tid;           // 16B units, 1536 total
      const int row = u / 24, uu = u - row*24;
      *(float4*)(xs + row*200 + uu*8) = *(const float4*)(src + u*8);
    }
  }

  const int lane = tid & 63;
  const int wv = tid >> 6;
  const int g = lane >> 4;
  const int r = lane & 15;
  const int wf = (wv & 1) * 32;     // feature half
  const int wt = (wv >> 1) * 32;    // token half
  const int wbw  = tok0 >> 8;
  const int nbase = (tok0 & 255) + wt;
  _Float16* scr = wsm + wv * 1280;  // wave-private scratch (after mfma barrier)

  for (int sub = 0; sub < 3; sub++) {
    const int feat0 = part*192 + sub*64;
    // ---- stage w tile: contiguous fp16 copy ----
    {
      const _Float16* src = wh + (size_t)feat0 * CC;
      #pragma unroll
      for (int it = 0; it < 6; it++) {
        const int u = it*256 + tid;
        const int row = u / 24, uu = u - row*24;
        *(float4*)(wsm + row*200 + uu*8) = *(const float4*)(src + u*8);
      }
    }
    __syncthreads();

    f32x4 acc[2][2];
    #pragma unroll
    for (int f = 0; f < 2; f++)
      #pragma unroll
      for (int t = 0; t < 2; t++) acc[f][t] = (f32x4){0.f,0.f,0.f,0.f};

    const _Float16* wbase = wsm + (wf + r)*200 + g*8;
    const _Float16* xbase = xs + (wt + r)*200 + g*8;
    #pragma unroll
    for (int ks = 0; ks < 6; ks++) {
      half8v af[2], bf[2];
      #pragma unroll
      for (int f = 0; f < 2; f++) af[f] = *(const half8v*)(wbase + f*16*200 + ks*32);
      #pragma unroll
      for (int t = 0; t < 2; t++) bf[t] = *(const half8v*)(xbase + t*16*200 + ks*32);
      #pragma unroll
      for (int f = 0; f < 2; f++)
        #pragma unroll
        for (int t = 0; t < 2; t++)
          acc[f][t] = mfma_k32(af[f], bf[t], acc[f][t]);
    }
    __syncthreads();   // wsm consumed; safe to use as epilogue scratch

    const int hloc = sub*2 + (wf >> 5);          // head 0..5
    const size_t slice = ((size_t)wbw * 6 + hloc) * 8192;

    if (part < 2) {
      float4 qb4[2];
      float scale = 1.f;
      if (part == 0) {
        #pragma unroll
        for (int f = 0; f < 2; f++)
          qb4[f] = *(const float4*)(q_bias + hloc*32 + f*16 + g*4);
        scale = __expf(fminf(ls[hloc], LOG100)) * LOG2E; // exp2-domain softmax
      } else {
        qb4[0] = make_float4(0.f,0.f,0.f,0.f);
        qb4[1] = make_float4(0.f,0.f,0.f,0.f);
      }
      #pragma unroll
      for (int t = 0; t < 2; t++) {
        float v0[2][4];
        float ss = 0.f;
        #pragma unroll
        for (int f = 0; f < 2; f++) {
          const float* qbp = (const float*)&qb4[f];
          #pragma unroll
          for (int j2 = 0; j2 < 4; j2++) {
            const float val = acc[f][t][j2] + qbp[j2];
            v0[f][j2] = val;
            ss = fmaf(val, val, ss);
          }
        }
        ss += __shfl_xor(ss, 16);
        ss += __shfl_xor(ss, 32);
        const float rn = scale / (sqrtf(ss) + 1e-12f);
        #pragma unroll
        for (int f = 0; f < 2; f++) {
          half4v hv;
          #pragma unroll
          for (int j2 = 0; j2 < 4; j2++) hv[j2] = (_Float16)(v0[f][j2] * rn);
          *(half4v*)(scr + (t*16 + r)*40 + f*16 + g*4) = hv;
        }
      }
      _Float16* dst = (part == 0 ? qh : kh) + slice;
      const int tl = lane >> 1;
      const int sel = (lane & 1) * 16;
      #pragma unroll
      for (int i8 = 0; i8 < 2; i8++) {
        const float4 vv = *(float4*)(scr + tl*40 + sel + i8*8);
        *(float4*)(dst + (size_t)(nbase + tl)*32 + sel + i8*8) = vv;
      }
    } else {
      float4 vb4[2];
      #pragma unroll
      for (int f = 0; f < 2; f++)
        vb4[f] = *(const float4*)(v_bias + hloc*32 + f*16 + g*4);
      #pragma unroll
      for (int t = 0; t < 2; t++) {
        #pragma unroll
        for (int f = 0; f < 2; f++) {
          const float* vbp = (const float*)&vb4[f];
          #pragma unroll
          for (int j2 = 0; j2 < 4; j2++)
            scr[(f*16 + g*4 + j2)*40 + t*16 + r] =
                (_Float16)(acc[f][t][j2] + vbp[j2]);
        }
      }
      _Float16* dst = vhT + slice;
      const int drow = lane >> 1;      // dim 0..31
      const int sel = (lane & 1) * 16;
      #pragma unroll
      for (int i8 = 0; i8 < 2; i8++) {
        const float4 vv = *(float4*)(scr + drow*40 + sel + i8*8);
        *(float4*)(dst + (size_t)drow*256 + nbase + sel + i8*8) = vv;
      }
    }
    if (sub < 2) __syncthreads();   // scr reads done before next w staging
  }
}

// ---------------------------------------------------------------------------
// MFMA attention (R13 config, no skip branch). 2 blocks per (window,head),
// 128 queries each; each wave owns 2 query tiles (K/V frags shared).
// XCD-swizzled. rpb via compact per-head LDS table in log2 domain.
// ah written in slice layout [bx][n][32].
// ---------------------------------------------------------------------------
__global__ __launch_bounds__(256) void attn_kernel(
    const _Float16* __restrict__ qh, const _Float16* __restrict__ kh,
    const _Float16* __restrict__ vhT, const float* __restrict__ Rtab,
    _Float16* __restrict__ ah)
{
  __shared__ half8v kf[16][64];
  __shared__ half4v vf[16][2][64];
  __shared__ float Rt[961];
  const int tid = threadIdx.x;
  const int hw = blockIdx.x;
  const int bid = (hw & 7) * 216 + (hw >> 3);   // XCD swizzle (1728 = 8*216)
  const int bx = bid >> 1;            // wb*6 + h
  const int qhalf = bid & 1;          // 128-query half
  const int wb = bx / 6;
  const int h  = bx - wb*6;
  const size_t slice = (size_t)bx * 8192;

  {
    const int j = tid >> 4, rr = tid & 15;
    const _Float16* src = kh + slice + (size_t)tid * 32;
    #pragma unroll
    for (int g4 = 0; g4 < 4; g4++)
      kf[j][16*g4 + rr] = *(const half8v*)(src + g4*8);
  }
  {
    const int mc = tid >> 4, rr = tid & 15;
    #pragma unroll
    for (int dt = 0; dt < 2; dt++) {
      const _Float16* src = vhT + slice + (size_t)(dt*16 + rr)*256 + mc*16;
      #pragma unroll
      for (int g4 = 0; g4 < 4; g4++)
        vf[mc][dt][16*g4 + rr] = *(const half4v*)(src + g4*4);
    }
  }
  for (int u = tid; u < 961; u += 256) Rt[u] = Rtab[h*961 + u];

  const int lane = tid & 63;
  const int wv   = tid >> 6;
  const int g    = lane >> 4;
  const int c    = lane & 15;
  const int n0   = qhalf*128 + wv*32 + c;   // first query row (tiles: +0, +16)
  const int nhi0 = qhalf*8 + wv*2;          // wave-uniform row-tile index

  const int wq = wb % 36;
  const int wy = wq / 6;
  const int wx = wq - wy*6;
  const bool lastY = (wy == 5);
  const float xm = ((wx == 5) && ((c >= 8) != (g >= 2))) ? -100000.f : 0.f;
  const int A3 = c - 4*g + 12;          // reversed-read base within R row

  half8v bq[2];
  #pragma unroll
  for (int ii = 0; ii < 2; ii++)
    bq[ii] = *(const half8v*)(qh + slice + (size_t)(n0 + ii*16)*32 + 8*g);

  __syncthreads();

  f32x4 o0[2], o1[2];
  float dsum[2];
  #pragma unroll
  for (int ii = 0; ii < 2; ii++) {
    o0[ii] = (f32x4){0.f,0.f,0.f,0.f};
    o1[ii] = (f32x4){0.f,0.f,0.f,0.f};
    dsum[ii] = 0.f;
  }

  #pragma unroll
  for (int j = 0; j < 16; j++) {
    const half8v kv = kf[j][lane];
    const half4v v0 = vf[j][0][lane];
    const half4v v1 = vf[j][1][lane];
    #pragma unroll
    for (int ii = 0; ii < 2; ii++) {
      const int nhi = nhi0 + ii;
      const float* rb = &Rt[(nhi - j + 15)*31 + A3];
      const float ym = (lastY && ((nhi >= 8) != (j >= 8))) ? -100000.f : 0.f;
      const float madd = xm + ym;
      f32x4 zero = {0.f,0.f,0.f,0.f};
      f32x4 s = mfma_k32(kv, bq[ii], zero);
      const float p0 = exp2fast(s[0] + rb[3] + madd);
      const float p1 = exp2fast(s[1] + rb[2] + madd);
      const float p2 = exp2fast(s[2] + rb[1] + madd);
      const float p3 = exp2fast(s[3] + rb[0] + madd);
      dsum[ii] += (p0 + p1) + (p2 + p3);
      half4v pf;
      pf[0]=(_Float16)p0; pf[1]=(_Float16)p1;
      pf[2]=(_Float16)p2; pf[3]=(_Float16)p3;
      o0[ii] = mfma_k16(v0, pf, o0[ii]);
      o1[ii] = mfma_k16(v1, pf, o1[ii]);
    }
  }

  #pragma unroll
  for (int ii = 0; ii < 2; ii++) {
    float d = dsum[ii] + __shfl_xor(dsum[ii], 16);
    d += __shfl_xor(d, 32);
    const float inv = 1.f / d;
    _Float16* obase = ah + slice + (size_t)(n0 + ii*16)*32 + 4*g;
    half4v h0, h1;
    #pragma unroll
    for (int j2 = 0; j2 < 4; j2++) {
      h0[j2] = (_Float16)(o0[ii][j2] * inv);
      h1[j2] = (_Float16)(o1[ii][j2] * inv);
    }
    *(half4v*)obase = h0;
    *(half4v*)(obase + 16) = h1;
  }
}

// ---------------------------------------------------------------------------
// proj_mfma: C[out-feature][token] = Pw x A^T, fp16 MFMA, f32 scatter out.
// A gathered from ah slice layout; proj_w staged as contiguous fp16 copy.
// ---------------------------------------------------------------------------
__global__ __launch_bounds__(256) void proj_mfma(
    const _Float16* __restrict__ ah, const _Float16* __restrict__ ph,
    const float* __restrict__ pb, float* __restrict__ out)
{
  __shared__ _Float16 xs[128*200];
  __shared__ _Float16 wsm[64*200];
  const int tid = threadIdx.x;
  const int tok0 = blockIdx.x * 128;
  const int feat0 = blockIdx.y * 64;

  {
    const int wb2 = tok0 >> 8;
    const int nb0 = tok0 & 255;
    #pragma unroll
    for (int it = 0; it < 12; it++) {
      const int u = it*256 + tid;            // 16B units, 3072 total
      const int row = u / 24, uu = u - row*24;
      const int hh = uu >> 2;                // head of this 16B chunk
      const int dd = (uu & 3) * 8;           // dim offset within head
      const _Float16* src = ah + ((size_t)(wb2*6 + hh))*8192
                               + (size_t)(nb0 + row)*32 + dd;
      *(float4*)(xs + row*200 + uu*8) = *(const float4*)src;
    }
    const _Float16* src = ph + (size_t)feat0 * CC;
    #pragma unroll
    for (int it = 0; it < 6; it++) {
      const int u = it*256 + tid;
      const int row = u / 24, uu = u - row*24;
      *(float4*)(wsm + row*200 + uu*8) = *(const float4*)(src + u*8);
    }
  }
  __syncthreads();

  const int lane = tid & 63;
  const int wv = tid >> 6;
  const int g = lane >> 4;
  const int r = lane & 15;
  const int wf = (wv & 1) * 32;
  const int wt = (wv >> 1) * 64;

  f32x4 acc[2][4];
  #pragma unroll
  for (int f = 0; f < 2; f++)
    #pragma unroll
    for (int t = 0; t < 4; t++) acc[f][t] = (f32x4){0.f,0.f,0.f,0.f};

  const _Float16* wbase = wsm + (wf + r)*200 + g*8;
  const _Float16* xbase = xs + (wt + r)*200 + g*8;
  #pragma unroll
  for (int ks = 0; ks < 6; ks++) {
    half8v af[2], bf[4];
    #pragma unroll
    for (int f = 0; f < 2; f++) af[f] = *(const half8v*)(wbase + f*16*200 + ks*32);
    #pragma unroll
    for (int t = 0; t < 4; t++) bf[t] = *(const half8v*)(xbase + t*16*200 + ks*32);
    #pragma unroll
    for (int f = 0; f < 2; f++)
      #pragma unroll
      for (int t = 0; t < 4; t++)
        acc[f][t] = mfma_k32(af[f], bf[t], acc[f][t]);
  }

  const int nf0 = feat0 + wf + g*4;
  float4 pb4[2];
  pb4[0] = *(const float4*)(pb + nf0);
  pb4[1] = *(const float4*)(pb + nf0 + 16);
  #pragma unroll
  for (int t = 0; t < 4; t++) {
    const int tg = tok0 + wt + t*16 + r;
    const int wb2 = tg >> 8;
    const int n2 = tg & 255;
    const int b = wb2 / 36;
    const int wq = wb2 - b*36;
    const int wy = wq / 6;
    const int wx = wq - wy*6;
    const int iy = (wy*16 + (n2 >> 4) + 8) % 96;
    const int ix = (wx*16 + (n2 & 15) + 8) % 96;
    float* obase = out + (size_t)((b*96 + iy)*96 + ix)*CC + nf0;
    #pragma unroll
    for (int f = 0; f < 2; f++) {
      const float* pbp = (const float*)&pb4[f];
      *(float4*)(obase + f*16) = make_float4(
          acc[f][t][0] + pbp[0], acc[f][t][1] + pbp[1],
          acc[f][t][2] + pbp[2], acc[f][t][3] + pbp[3]);
    }
  }
}

extern "C" void kernel_launch(void* const* d_in, const int* in_sizes, int n_in,
                              void* d_out, int out_size, void* d_ws, size_t ws_size,
                              hipStream_t stream) {
  const float* x      = (const float*)d_in[0];
  const float* qkv_w  = (const float*)d_in[1];
  const float* q_bias = (const float*)d_in[2];
  const float* v_bias = (const float*)d_in[3];
  const float* ls     = (const float*)d_in[4];
  const float* cpb_w1 = (const float*)d_in[5];
  const float* cpb_b1 = (const float*)d_in[6];
  const float* cpb_w2 = (const float*)d_in[7];
  const float* proj_w = (const float*)d_in[8];
  const float* proj_b = (const float*)d_in[9];
  const float* tab    = (const float*)d_in[10];
  float* out = (float*)d_out;

  char* wsb = (char*)d_ws;
  _Float16* qh  = (_Float16*)(wsb);
  _Float16* kh  = (_Float16*)(wsb + 1*14155776);
  _Float16* vhT = (_Float16*)(wsb + 2*14155776);
  _Float16* ah  = (_Float16*)(wsb + 3*14155776);
  _Float16* xh  = (_Float16*)(wsb + 4*14155776);
  float* Rtab   = (float*)(wsb + 5*14155776);
  _Float16* wh  = (_Float16*)(wsb + 5*14155776 + 32768);
  _Float16* ph  = (_Float16*)(wsb + 5*14155776 + 32768 + 221184);

  cvt_cpb<<<7297, 256, 0, stream>>>(x, xh, tab, cpb_w1, cpb_b1, cpb_w2,
                                    ls, Rtab, qkv_w, proj_w, wh, ph);
  qkv_mfma<<<dim3(576, 3), 256, 0, stream>>>(xh, wh, q_bias, v_bias, ls,
                                             qh, kh, vhT);
  attn_kernel<<<1728, 256, 0, stream>>>(qh, kh, vhT, Rtab, ah);
  proj_mfma<<<dim3(288, 3), 256, 0, stream>>>(ah, ph, proj_b, out);
}

// Round 19
// 73.728 us; speedup vs baseline: 1.0501x; 1.0501x over previous
//
#include <hip/hip_runtime.h>

#define CC 192
#define LOG100 4.6051701859880914f
#define PSHIFT 11.0f   // softmax-invariant scale: keeps fp16 P out of subnormals
#define LOG2E  1.4426950408889634f

typedef _Float16 half8v __attribute__((ext_vector_type(8)));
typedef _Float16 half4v __attribute__((ext_vector_type(4)));
typedef float f32x4 __attribute__((ext_vector_type(4)));

static __device__ __forceinline__ f32x4 mfma_k32(half8v a, half8v b, f32x4 c) {
#if __has_builtin(__builtin_amdgcn_mfma_f32_16x16x32_f16)
  return __builtin_amdgcn_mfma_f32_16x16x32_f16(a, b, c, 0, 0, 0);
#else
  asm("v_mfma_f32_16x16x32_f16 %0, %1, %2, %0" : "+v"(c) : "v"(a), "v"(b));
  return c;
#endif
}
static __device__ __forceinline__ f32x4 mfma_k16(half4v a, half4v b, f32x4 c) {
#if __has_builtin(__builtin_amdgcn_mfma_f32_16x16x16f16)
  return __builtin_amdgcn_mfma_f32_16x16x16f16(a, b, c, 0, 0, 0);
#else
  asm("v_mfma_f32_16x16x16_f16 %0, %1, %2, %0" : "+v"(c) : "v"(a), "v"(b));
  return c;
#endif
}
static __device__ __forceinline__ float exp2fast(float x) {
#if __has_builtin(__builtin_amdgcn_exp2f)
  return __builtin_amdgcn_exp2f(x);
#else
  return exp2f(x);
#endif
}

// ---------------------------------------------------------------------------
// cvt_cpb: fused prepass.
//   Blocks [0,6912):     roll+window gather f32->fp16 (xh)
//   Blocks [6912,7153):  CPB MLP -> Rtab (4 entries/block, 1 per wave)
//   Blocks [7153,7297):  qkv_w + proj_w f32 -> fp16 (wh, ph)
// ---------------------------------------------------------------------------
__global__ __launch_bounds__(256) void cvt_cpb(
    const float* __restrict__ x, _Float16* __restrict__ xh,
    const float* __restrict__ tab, const float* __restrict__ w1,
    const float* __restrict__ b1, const float* __restrict__ w2,
    const float* __restrict__ ls, float* __restrict__ Rtab,
    const float* __restrict__ qkvw, const float* __restrict__ projw,
    _Float16* __restrict__ wh, _Float16* __restrict__ ph)
{
  if (blockIdx.x < 6912) {
    const int q = blockIdx.x * 256 + threadIdx.x;   // float4 units: 36864*48
    const int token = q / 48;
    const int c4 = q - token * 48;
    const int wb = token >> 8;
    const int n = token & 255;
    const int b = wb / 36;
    const int wq = wb - b * 36;
    const int wy = wq / 6;
    const int wx = wq - wy * 6;
    const int iy = (wy * 16 + (n >> 4) + 8) % 96;
    const int ix = (wx * 16 + (n & 15) + 8) % 96;
    const float4 v = *(const float4*)(x + (size_t)((b * 96 + iy) * 96 + ix) * CC + c4 * 4);
    half4v hv = {(_Float16)v.x, (_Float16)v.y, (_Float16)v.z, (_Float16)v.w};
    *(half4v*)(xh + (size_t)token * CC + c4 * 4) = hv;
    return;
  }
  if (blockIdx.x >= 7153) {
    const int q = (blockIdx.x - 7153) * 256 + threadIdx.x;  // 0..36863 float4 units
    float4 v;
    _Float16* dst;
    int off;
    if (q < 27648) { v = *(const float4*)(qkvw + q * 4); dst = wh; off = q * 4; }
    else { const int p2 = q - 27648; v = *(const float4*)(projw + p2 * 4); dst = ph; off = p2 * 4; }
    half4v hv = {(_Float16)v.x, (_Float16)v.y, (_Float16)v.z, (_Float16)v.w};
    *(half4v*)(dst + off) = hv;
    return;
  }
  const int p = (blockIdx.x - 6912) * 4 + (threadIdx.x >> 6);
  if (p >= 961) return;
  const int lane = threadIdx.x & 63;
  const float t0 = tab[p*2+0];
  const float t1 = tab[p*2+1];
  float a0=0.f,a1=0.f,a2=0.f,a3=0.f,a4=0.f,a5=0.f;
  for (int j = lane; j < 512; j += 64) {
    float hv = fmaxf(fmaf(t0, w1[2*j], fmaf(t1, w1[2*j+1], b1[j])), 0.f);
    a0 = fmaf(hv, w2[0*512+j], a0);
    a1 = fmaf(hv, w2[1*512+j], a1);
    a2 = fmaf(hv, w2[2*512+j], a2);
    a3 = fmaf(hv, w2[3*512+j], a3);
    a4 = fmaf(hv, w2[4*512+j], a4);
    a5 = fmaf(hv, w2[5*512+j], a5);
  }
  #pragma unroll
  for (int off = 32; off > 0; off >>= 1) {
    a0 += __shfl_down(a0, off);
    a1 += __shfl_down(a1, off);
    a2 += __shfl_down(a2, off);
    a3 += __shfl_down(a3, off);
    a4 += __shfl_down(a4, off);
    a5 += __shfl_down(a5, off);
  }
  if (lane == 0) {
    float av[6] = {a0, a1, a2, a3, a4, a5};
    #pragma unroll
    for (int h = 0; h < 6; h++) {
      const float rpb = 16.f / (1.f + __expf(-av[h]));
      const float bound = __expf(fminf(ls[h], LOG100)) + 16.f;
      Rtab[h*961 + p] = (rpb - bound + PSHIFT) * LOG2E;
    }
  }
}

// ---------------------------------------------------------------------------
// qkv_mfma: 64 tok x 64 feat tiles, 1D grid 5184 with XCD-affinity swizzle:
// xcd = id&7 owns token tiles [xcd*72, xcd*72+72) x all 9 feature tiles ->
// per-XCD xh working set 1.8MB (fits 4MB L2), 8/9 xh re-reads become L2 hits.
// Epilogue: bias + cosine-norm + log2e scale; qh/kh [n][d], v [d][n].
// ---------------------------------------------------------------------------
__global__ __launch_bounds__(256) void qkv_mfma(
    const _Float16* __restrict__ xh, const _Float16* __restrict__ wh,
    const float* __restrict__ q_bias, const float* __restrict__ v_bias,
    const float* __restrict__ ls,
    _Float16* __restrict__ qh, _Float16* __restrict__ kh,
    _Float16* __restrict__ vhT)
{
  __shared__ _Float16 xs[64*200];
  __shared__ _Float16 wsm[64*200];
  const int tid = threadIdx.x;
  const int id = blockIdx.x;
  const int xcd = id & 7;
  const int local = id >> 3;            // 0..647
  const int lt = local / 9;             // 0..71
  const int ft = local - lt*9;          // feature tile 0..8
  const int tok0 = (xcd*72 + lt) * 64;
  const int feat0 = ft * 64;

  // ---- stage x tile: contiguous fp16 copy ----
  {
    const _Float16* src = xh + (size_t)tok0 * CC;
    #pragma unroll
    for (int it = 0; it < 6; it++) {
      const int u = it*256 + tid;           // 16B units, 1536 total
      const int row = u / 24, uu = u - row*24;
      *(float4*)(xs + row*200 + uu*8) = *(const float4*)(src + u*8);
    }
  }
  // ---- stage w tile: contiguous fp16 copy ----
  {
    const _Float16* src = wh + (size_t)feat0 * CC;
    #pragma unroll
    for (int it = 0; it < 6; it++) {
      const int u = it*256 + tid;           // 1536 units
      const int row = u / 24, uu = u - row*24;
      *(float4*)(wsm + row*200 + uu*8) = *(const float4*)(src + u*8);
    }
  }
  __syncthreads();

  const int lane = tid & 63;
  const int wv = tid >> 6;
  const int g = lane >> 4;
  const int r = lane & 15;
  const int wf = (wv & 1) * 32;     // feature half
  const int wt = (wv >> 1) * 32;    // token half

  f32x4 acc[2][2];
  #pragma unroll
  for (int f = 0; f < 2; f++)
    #pragma unroll
    for (int t = 0; t < 2; t++) acc[f][t] = (f32x4){0.f,0.f,0.f,0.f};

  const _Float16* wbase = wsm + (wf + r)*200 + g*8;
  const _Float16* xbase = xs + (wt + r)*200 + g*8;
  #pragma unroll
  for (int ks = 0; ks < 6; ks++) {
    half8v af[2], bf[2];
    #pragma unroll
    for (int f = 0; f < 2; f++) af[f] = *(const half8v*)(wbase + f*16*200 + ks*32);
    #pragma unroll
    for (int t = 0; t < 2; t++) bf[t] = *(const half8v*)(xbase + t*16*200 + ks*32);
    #pragma unroll
    for (int f = 0; f < 2; f++)
      #pragma unroll
      for (int t = 0; t < 2; t++)
        acc[f][t] = mfma_k32(af[f], bf[t], acc[f][t]);
  }
  __syncthreads();    // tiles consumed; reuse xs as scratch

  const int part = ft / 3;                       // 0=q 1=k 2=v
  const int hloc = (ft - part*3) * 2 + (wf >> 5);     // head 0..5
  const int wbw  = tok0 >> 8;
  const int nbase = (tok0 & 255) + wt;
  const size_t slice = ((size_t)wbw * 6 + hloc) * 8192;
  _Float16* scr = xs + wv * 1280;

  if (part < 2) {
    float4 qb4[2];
    float scale = 1.f;
    if (part == 0) {
      #pragma unroll
      for (int f = 0; f < 2; f++)
        qb4[f] = *(const float4*)(q_bias + hloc*32 + f*16 + g*4);
      scale = __expf(fminf(ls[hloc], LOG100)) * LOG2E;   // exp2-domain softmax
    } else {
      qb4[0] = make_float4(0.f,0.f,0.f,0.f);
      qb4[1] = make_float4(0.f,0.f,0.f,0.f);
    }
    #pragma unroll
    for (int t = 0; t < 2; t++) {
      float v0[2][4];
      float ss = 0.f;
      #pragma unroll
      for (int f = 0; f < 2; f++) {
        const float* qbp = (const float*)&qb4[f];
        #pragma unroll
        for (int j2 = 0; j2 < 4; j2++) {
          const float val = acc[f][t][j2] + qbp[j2];
          v0[f][j2] = val;
          ss = fmaf(val, val, ss);
        }
      }
      ss += __shfl_xor(ss, 16);
      ss += __shfl_xor(ss, 32);
      const float rn = scale / (sqrtf(ss) + 1e-12f);
      #pragma unroll
      for (int f = 0; f < 2; f++) {
        half4v hv;
        #pragma unroll
        for (int j2 = 0; j2 < 4; j2++) hv[j2] = (_Float16)(v0[f][j2] * rn);
        *(half4v*)(scr + (t*16 + r)*40 + f*16 + g*4) = hv;
      }
    }
    _Float16* dst = (part == 0 ? qh : kh) + slice;
    const int tl = lane >> 1;
    const int sel = (lane & 1) * 16;
    #pragma unroll
    for (int i8 = 0; i8 < 2; i8++) {
      const float4 vv = *(float4*)(scr + tl*40 + sel + i8*8);
      *(float4*)(dst + (size_t)(nbase + tl)*32 + sel + i8*8) = vv;
    }
  } else {
    float4 vb4[2];
    #pragma unroll
    for (int f = 0; f < 2; f++)
      vb4[f] = *(const float4*)(v_bias + hloc*32 + f*16 + g*4);
    #pragma unroll
    for (int t = 0; t < 2; t++) {
      #pragma unroll
      for (int f = 0; f < 2; f++) {
        const float* vbp = (const float*)&vb4[f];
        #pragma unroll
        for (int j2 = 0; j2 < 4; j2++)
          scr[(f*16 + g*4 + j2)*40 + t*16 + r] =
              (_Float16)(acc[f][t][j2] + vbp[j2]);
      }
    }
    _Float16* dst = vhT + slice;
    const int drow = lane >> 1;      // dim 0..31
    const int sel = (lane & 1) * 16;
    #pragma unroll
    for (int i8 = 0; i8 < 2; i8++) {
      const float4 vv = *(float4*)(scr + drow*40 + sel + i8*8);
      *(float4*)(dst + (size_t)drow*256 + nbase + sel + i8*8) = vv;
    }
  }
}

// ---------------------------------------------------------------------------
// MFMA attention (R13 config, no skip branch). 2 blocks per (window,head),
// 128 queries each; each wave owns 2 query tiles (K/V frags shared).
// XCD-swizzled. rpb via compact per-head LDS table in log2 domain.
// ah written in slice layout [bx][n][32].
// ---------------------------------------------------------------------------
__global__ __launch_bounds__(256) void attn_kernel(
    const _Float16* __restrict__ qh, const _Float16* __restrict__ kh,
    const _Float16* __restrict__ vhT, const float* __restrict__ Rtab,
    _Float16* __restrict__ ah)
{
  __shared__ half8v kf[16][64];
  __shared__ half4v vf[16][2][64];
  __shared__ float Rt[961];
  const int tid = threadIdx.x;
  const int hw = blockIdx.x;
  const int bid = (hw & 7) * 216 + (hw >> 3);   // XCD swizzle (1728 = 8*216)
  const int bx = bid >> 1;            // wb*6 + h
  const int qhalf = bid & 1;          // 128-query half
  const int wb = bx / 6;
  const int h  = bx - wb*6;
  const size_t slice = (size_t)bx * 8192;

  {
    const int j = tid >> 4, rr = tid & 15;
    const _Float16* src = kh + slice + (size_t)tid * 32;
    #pragma unroll
    for (int g4 = 0; g4 < 4; g4++)
      kf[j][16*g4 + rr] = *(const half8v*)(src + g4*8);
  }
  {
    const int mc = tid >> 4, rr = tid & 15;
    #pragma unroll
    for (int dt = 0; dt < 2; dt++) {
      const _Float16* src = vhT + slice + (size_t)(dt*16 + rr)*256 + mc*16;
      #pragma unroll
      for (int g4 = 0; g4 < 4; g4++)
        vf[mc][dt][16*g4 + rr] = *(const half4v*)(src + g4*4);
    }
  }
  for (int u = tid; u < 961; u += 256) Rt[u] = Rtab[h*961 + u];

  const int lane = tid & 63;
  const int wv   = tid >> 6;
  const int g    = lane >> 4;
  const int c    = lane & 15;
  const int n0   = qhalf*128 + wv*32 + c;   // first query row (tiles: +0, +16)
  const int nhi0 = qhalf*8 + wv*2;          // wave-uniform row-tile index

  const int wq = wb % 36;
  const int wy = wq / 6;
  const int wx = wq - wy*6;
  const bool lastY = (wy == 5);
  const float xm = ((wx == 5) && ((c >= 8) != (g >= 2))) ? -100000.f : 0.f;
  const int A3 = c - 4*g + 12;          // reversed-read base within R row

  half8v bq[2];
  #pragma unroll
  for (int ii = 0; ii < 2; ii++)
    bq[ii] = *(const half8v*)(qh + slice + (size_t)(n0 + ii*16)*32 + 8*g);

  __syncthreads();

  f32x4 o0[2], o1[2];
  float dsum[2];
  #pragma unroll
  for (int ii = 0; ii < 2; ii++) {
    o0[ii] = (f32x4){0.f,0.f,0.f,0.f};
    o1[ii] = (f32x4){0.f,0.f,0.f,0.f};
    dsum[ii] = 0.f;
  }

  #pragma unroll
  for (int j = 0; j < 16; j++) {
    const half8v kv = kf[j][lane];
    const half4v v0 = vf[j][0][lane];
    const half4v v1 = vf[j][1][lane];
    #pragma unroll
    for (int ii = 0; ii < 2; ii++) {
      const int nhi = nhi0 + ii;
      const float* rb = &Rt[(nhi - j + 15)*31 + A3];
      const float ym = (lastY && ((nhi >= 8) != (j >= 8))) ? -100000.f : 0.f;
      const float madd = xm + ym;
      f32x4 zero = {0.f,0.f,0.f,0.f};
      f32x4 s = mfma_k32(kv, bq[ii], zero);
      const float p0 = exp2fast(s[0] + rb[3] + madd);
      const float p1 = exp2fast(s[1] + rb[2] + madd);
      const float p2 = exp2fast(s[2] + rb[1] + madd);
      const float p3 = exp2fast(s[3] + rb[0] + madd);
      dsum[ii] += (p0 + p1) + (p2 + p3);
      half4v pf;
      pf[0]=(_Float16)p0; pf[1]=(_Float16)p1;
      pf[2]=(_Float16)p2; pf[3]=(_Float16)p3;
      o0[ii] = mfma_k16(v0, pf, o0[ii]);
      o1[ii] = mfma_k16(v1, pf, o1[ii]);
    }
  }

  #pragma unroll
  for (int ii = 0; ii < 2; ii++) {
    float d = dsum[ii] + __shfl_xor(dsum[ii], 16);
    d += __shfl_xor(d, 32);
    const float inv = 1.f / d;
    _Float16* obase = ah + slice + (size_t)(n0 + ii*16)*32 + 4*g;
    half4v h0, h1;
    #pragma unroll
    for (int j2 = 0; j2 < 4; j2++) {
      h0[j2] = (_Float16)(o0[ii][j2] * inv);
      h1[j2] = (_Float16)(o1[ii][j2] * inv);
    }
    *(half4v*)obase = h0;
    *(half4v*)(obase + 16) = h1;
  }
}

// ---------------------------------------------------------------------------
// proj_mfma: 1D grid 864 with XCD-affinity swizzle (8 x 36 token-tiles x 3
// feature tiles): per-XCD ah working set 1.8MB -> L2-resident re-reads.
// C[out-feature][token] = Pw x A^T, fp16 MFMA, f32 scatter out.
// ---------------------------------------------------------------------------
__global__ __launch_bounds__(256) void proj_mfma(
    const _Float16* __restrict__ ah, const _Float16* __restrict__ ph,
    const float* __restrict__ pb, float* __restrict__ out)
{
  __shared__ _Float16 xs[128*200];
  __shared__ _Float16 wsm[64*200];
  const int tid = threadIdx.x;
  const int id = blockIdx.x;
  const int xcd = id & 7;
  const int local = id >> 3;            // 0..107
  const int lt = local / 3;             // 0..35
  const int ft = local - lt*3;          // 0..2
  const int tok0 = (xcd*36 + lt) * 128;
  const int feat0 = ft * 64;

  {
    const int wb2 = tok0 >> 8;
    const int nb0 = tok0 & 255;
    #pragma unroll
    for (int it = 0; it < 12; it++) {
      const int u = it*256 + tid;            // 16B units, 3072 total
      const int row = u / 24, uu = u - row*24;
      const int hh = uu >> 2;                // head of this 16B chunk
      const int dd = (uu & 3) * 8;           // dim offset within head
      const _Float16* src = ah + ((size_t)(wb2*6 + hh))*8192
                               + (size_t)(nb0 + row)*32 + dd;
      *(float4*)(xs + row*200 + uu*8) = *(const float4*)src;
    }
    const _Float16* src = ph + (size_t)feat0 * CC;
    #pragma unroll
    for (int it = 0; it < 6; it++) {
      const int u = it*256 + tid;
      const int row = u / 24, uu = u - row*24;
      *(float4*)(wsm + row*200 + uu*8) = *(const float4*)(src + u*8);
    }
  }
  __syncthreads();

  const int lane = tid & 63;
  const int wv = tid >> 6;
  const int g = lane >> 4;
  const int r = lane & 15;
  const int wf = (wv & 1) * 32;
  const int wt = (wv >> 1) * 64;

  f32x4 acc[2][4];
  #pragma unroll
  for (int f = 0; f < 2; f++)
    #pragma unroll
    for (int t = 0; t < 4; t++) acc[f][t] = (f32x4){0.f,0.f,0.f,0.f};

  const _Float16* wbase = wsm + (wf + r)*200 + g*8;
  const _Float16* xbase = xs + (wt + r)*200 + g*8;
  #pragma unroll
  for (int ks = 0; ks < 6; ks++) {
    half8v af[2], bf[4];
    #pragma unroll
    for (int f = 0; f < 2; f++) af[f] = *(const half8v*)(wbase + f*16*200 + ks*32);
    #pragma unroll
    for (int t = 0; t < 4; t++) bf[t] = *(const half8v*)(xbase + t*16*200 + ks*32);
    #pragma unroll
    for (int f = 0; f < 2; f++)
      #pragma unroll
      for (int t = 0; t < 4; t++)
        acc[f][t] = mfma_k32(af[f], bf[t], acc[f][t]);
  }

  const int nf0 = feat0 + wf + g*4;
  float4 pb4[2];
  pb4[0] = *(const float4*)(pb + nf0);
  pb4[1] = *(const float4*)(pb + nf0 + 16);
  #pragma unroll
  for (int t = 0; t < 4; t++) {
    const int tg = tok0 + wt + t*16 + r;
    const int wb2 = tg >> 8;
    const int n2 = tg & 255;
    const int b = wb2 / 36;
    const int wq = wb2 - b*36;
    const int wy = wq / 6;
    const int wx = wq - wy*6;
    const int iy = (wy*16 + (n2 >> 4) + 8) % 96;
    const int ix = (wx*16 + (n2 & 15) + 8) % 96;
    float* obase = out + (size_t)((b*96 + iy)*96 + ix)*CC + nf0;
    #pragma unroll
    for (int f = 0; f < 2; f++) {
      const float* pbp = (const float*)&pb4[f];
      *(float4*)(obase + f*16) = make_float4(
          acc[f][t][0] + pbp[0], acc[f][t][1] + pbp[1],
          acc[f][t][2] + pbp[2], acc[f][t][3] + pbp[3]);
    }
  }
}

extern "C" void kernel_launch(void* const* d_in, const int* in_sizes, int n_in,
                              void* d_out, int out_size, void* d_ws, size_t ws_size,
                              hipStream_t stream) {
  const float* x      = (const float*)d_in[0];
  const float* qkv_w  = (const float*)d_in[1];
  const float* q_bias = (const float*)d_in[2];
  const float* v_bias = (const float*)d_in[3];
  const float* ls     = (const float*)d_in[4];
  const float* cpb_w1 = (const float*)d_in[5];
  const float* cpb_b1 = (const float*)d_in[6];
  const float* cpb_w2 = (const float*)d_in[7];
  const float* proj_w = (const float*)d_in[8];
  const float* proj_b = (const float*)d_in[9];
  const float* tab    = (const float*)d_in[10];
  float* out = (float*)d_out;

  char* wsb = (char*)d_ws;
  _Float16* qh  = (_Float16*)(wsb);
  _Float16* kh  = (_Float16*)(wsb + 1*14155776);
  _Float16* vhT = (_Float16*)(wsb + 2*14155776);
  _Float16* ah  = (_Float16*)(wsb + 3*14155776);
  _Float16* xh  = (_Float16*)(wsb + 4*14155776);
  float* Rtab   = (float*)(wsb + 5*14155776);
  _Float16* wh  = (_Float16*)(wsb + 5*14155776 + 32768);
  _Float16* ph  = (_Float16*)(wsb + 5*14155776 + 32768 + 221184);

  cvt_cpb<<<7297, 256, 0, stream>>>(x, xh, tab, cpb_w1, cpb_b1, cpb_w2,
                                    ls, Rtab, qkv_w, proj_w, wh, ph);
  qkv_mfma<<<5184, 256, 0, stream>>>(xh, wh, q_bias, v_bias, ls,
                                     qh, kh, vhT);
  attn_kernel<<<1728, 256, 0, stream>>>(qh, kh, vhT, Rtab, ah);
  proj_mfma<<<864, 256, 0, stream>>>(ah, ph, proj_b, out);
}

// Round 20
// 72.211 us; speedup vs baseline: 1.0721x; 1.0210x over previous
//
#include <hip/hip_runtime.h>

#define CC 192
#define LOG100 4.6051701859880914f
#define PSHIFT 11.0f   // softmax-invariant scale: keeps fp16 P out of subnormals
#define LOG2E  1.4426950408889634f

typedef _Float16 half8v __attribute__((ext_vector_type(8)));
typedef _Float16 half4v __attribute__((ext_vector_type(4)));
typedef float f32x4 __attribute__((ext_vector_type(4)));

static __device__ __forceinline__ f32x4 mfma_k32(half8v a, half8v b, f32x4 c) {
#if __has_builtin(__builtin_amdgcn_mfma_f32_16x16x32_f16)
  return __builtin_amdgcn_mfma_f32_16x16x32_f16(a, b, c, 0, 0, 0);
#else
  asm("v_mfma_f32_16x16x32_f16 %0, %1, %2, %0" : "+v"(c) : "v"(a), "v"(b));
  return c;
#endif
}
static __device__ __forceinline__ f32x4 mfma_k16(half4v a, half4v b, f32x4 c) {
#if __has_builtin(__builtin_amdgcn_mfma_f32_16x16x16f16)
  return __builtin_amdgcn_mfma_f32_16x16x16f16(a, b, c, 0, 0, 0);
#else
  asm("v_mfma_f32_16x16x16_f16 %0, %1, %2, %0" : "+v"(c) : "v"(a), "v"(b));
  return c;
#endif
}
static __device__ __forceinline__ float exp2fast(float x) {
#if __has_builtin(__builtin_amdgcn_exp2f)
  return __builtin_amdgcn_exp2f(x);
#else
  return exp2f(x);
#endif
}

// ---------------------------------------------------------------------------
// cvt_cpb: fused prepass.
//   Blocks [0,6912):     roll+window gather f32->fp16 (xh)
//   Blocks [6912,7153):  CPB MLP -> Rtab (4 entries/block, 1 per wave)
//   Blocks [7153,7297):  qkv_w + proj_w f32 -> fp16 (wh, ph)
// ---------------------------------------------------------------------------
__global__ __launch_bounds__(256) void cvt_cpb(
    const float* __restrict__ x, _Float16* __restrict__ xh,
    const float* __restrict__ tab, const float* __restrict__ w1,
    const float* __restrict__ b1, const float* __restrict__ w2,
    const float* __restrict__ ls, float* __restrict__ Rtab,
    const float* __restrict__ qkvw, const float* __restrict__ projw,
    _Float16* __restrict__ wh, _Float16* __restrict__ ph)
{
  if (blockIdx.x < 6912) {
    const int q = blockIdx.x * 256 + threadIdx.x;   // float4 units: 36864*48
    const int token = q / 48;
    const int c4 = q - token * 48;
    const int wb = token >> 8;
    const int n = token & 255;
    const int b = wb / 36;
    const int wq = wb - b * 36;
    const int wy = wq / 6;
    const int wx = wq - wy * 6;
    const int iy = (wy * 16 + (n >> 4) + 8) % 96;
    const int ix = (wx * 16 + (n & 15) + 8) % 96;
    const float4 v = *(const float4*)(x + (size_t)((b * 96 + iy) * 96 + ix) * CC + c4 * 4);
    half4v hv = {(_Float16)v.x, (_Float16)v.y, (_Float16)v.z, (_Float16)v.w};
    *(half4v*)(xh + (size_t)token * CC + c4 * 4) = hv;
    return;
  }
  if (blockIdx.x >= 7153) {
    const int q = (blockIdx.x - 7153) * 256 + threadIdx.x;  // 0..36863 float4 units
    float4 v;
    _Float16* dst;
    int off;
    if (q < 27648) { v = *(const float4*)(qkvw + q * 4); dst = wh; off = q * 4; }
    else { const int p2 = q - 27648; v = *(const float4*)(projw + p2 * 4); dst = ph; off = p2 * 4; }
    half4v hv = {(_Float16)v.x, (_Float16)v.y, (_Float16)v.z, (_Float16)v.w};
    *(half4v*)(dst + off) = hv;
    return;
  }
  const int p = (blockIdx.x - 6912) * 4 + (threadIdx.x >> 6);
  if (p >= 961) return;
  const int lane = threadIdx.x & 63;
  const float t0 = tab[p*2+0];
  const float t1 = tab[p*2+1];
  float a0=0.f,a1=0.f,a2=0.f,a3=0.f,a4=0.f,a5=0.f;
  for (int j = lane; j < 512; j += 64) {
    float hv = fmaxf(fmaf(t0, w1[2*j], fmaf(t1, w1[2*j+1], b1[j])), 0.f);
    a0 = fmaf(hv, w2[0*512+j], a0);
    a1 = fmaf(hv, w2[1*512+j], a1);
    a2 = fmaf(hv, w2[2*512+j], a2);
    a3 = fmaf(hv, w2[3*512+j], a3);
    a4 = fmaf(hv, w2[4*512+j], a4);
    a5 = fmaf(hv, w2[5*512+j], a5);
  }
  #pragma unroll
  for (int off = 32; off > 0; off >>= 1) {
    a0 += __shfl_down(a0, off);
    a1 += __shfl_down(a1, off);
    a2 += __shfl_down(a2, off);
    a3 += __shfl_down(a3, off);
    a4 += __shfl_down(a4, off);
    a5 += __shfl_down(a5, off);
  }
  if (lane == 0) {
    float av[6] = {a0, a1, a2, a3, a4, a5};
    #pragma unroll
    for (int h = 0; h < 6; h++) {
      const float rpb = 16.f / (1.f + __expf(-av[h]));
      const float bound = __expf(fminf(ls[h], LOG100)) + 16.f;
      Rtab[h*961 + p] = (rpb - bound + PSHIFT) * LOG2E;
    }
  }
}

// ---------------------------------------------------------------------------
// qkv_mfma: 64 tok x 64 feat tiles, 1D grid 5184 with XCD-affinity swizzle.
// Epilogue: bias + cosine-norm + log2e scale; qh/kh [n][d], v [d][n].
// ---------------------------------------------------------------------------
__global__ __launch_bounds__(256) void qkv_mfma(
    const _Float16* __restrict__ xh, const _Float16* __restrict__ wh,
    const float* __restrict__ q_bias, const float* __restrict__ v_bias,
    const float* __restrict__ ls,
    _Float16* __restrict__ qh, _Float16* __restrict__ kh,
    _Float16* __restrict__ vhT)
{
  __shared__ _Float16 xs[64*200];
  __shared__ _Float16 wsm[64*200];
  const int tid = threadIdx.x;
  const int id = blockIdx.x;
  const int xcd = id & 7;
  const int local = id >> 3;            // 0..647
  const int lt = local / 9;             // 0..71
  const int ft = local - lt*9;          // feature tile 0..8
  const int tok0 = (xcd*72 + lt) * 64;
  const int feat0 = ft * 64;

  // ---- stage x tile: contiguous fp16 copy ----
  {
    const _Float16* src = xh + (size_t)tok0 * CC;
    #pragma unroll
    for (int it = 0; it < 6; it++) {
      const int u = it*256 + tid;           // 16B units, 1536 total
      const int row = u / 24, uu = u - row*24;
      *(float4*)(xs + row*200 + uu*8) = *(const float4*)(src + u*8);
    }
  }
  // ---- stage w tile: contiguous fp16 copy ----
  {
    const _Float16* src = wh + (size_t)feat0 * CC;
    #pragma unroll
    for (int it = 0; it < 6; it++) {
      const int u = it*256 + tid;           // 1536 units
      const int row = u / 24, uu = u - row*24;
      *(float4*)(wsm + row*200 + uu*8) = *(const float4*)(src + u*8);
    }
  }
  __syncthreads();

  const int lane = tid & 63;
  const int wv = tid >> 6;
  const int g = lane >> 4;
  const int r = lane & 15;
  const int wf = (wv & 1) * 32;     // feature half
  const int wt = (wv >> 1) * 32;    // token half

  f32x4 acc[2][2];
  #pragma unroll
  for (int f = 0; f < 2; f++)
    #pragma unroll
    for (int t = 0; t < 2; t++) acc[f][t] = (f32x4){0.f,0.f,0.f,0.f};

  const _Float16* wbase = wsm + (wf + r)*200 + g*8;
  const _Float16* xbase = xs + (wt + r)*200 + g*8;
  #pragma unroll
  for (int ks = 0; ks < 6; ks++) {
    half8v af[2], bf[2];
    #pragma unroll
    for (int f = 0; f < 2; f++) af[f] = *(const half8v*)(wbase + f*16*200 + ks*32);
    #pragma unroll
    for (int t = 0; t < 2; t++) bf[t] = *(const half8v*)(xbase + t*16*200 + ks*32);
    #pragma unroll
    for (int f = 0; f < 2; f++)
      #pragma unroll
      for (int t = 0; t < 2; t++)
        acc[f][t] = mfma_k32(af[f], bf[t], acc[f][t]);
  }
  __syncthreads();    // tiles consumed; reuse xs as scratch

  const int part = ft / 3;                       // 0=q 1=k 2=v
  const int hloc = (ft - part*3) * 2 + (wf >> 5);     // head 0..5
  const int wbw  = tok0 >> 8;
  const int nbase = (tok0 & 255) + wt;
  const size_t slice = ((size_t)wbw * 6 + hloc) * 8192;
  _Float16* scr = xs + wv * 1280;

  if (part < 2) {
    float4 qb4[2];
    float scale = 1.f;
    if (part == 0) {
      #pragma unroll
      for (int f = 0; f < 2; f++)
        qb4[f] = *(const float4*)(q_bias + hloc*32 + f*16 + g*4);
      scale = __expf(fminf(ls[hloc], LOG100)) * LOG2E;   // exp2-domain softmax
    } else {
      qb4[0] = make_float4(0.f,0.f,0.f,0.f);
      qb4[1] = make_float4(0.f,0.f,0.f,0.f);
    }
    #pragma unroll
    for (int t = 0; t < 2; t++) {
      float v0[2][4];
      float ss = 0.f;
      #pragma unroll
      for (int f = 0; f < 2; f++) {
        const float* qbp = (const float*)&qb4[f];
        #pragma unroll
        for (int j2 = 0; j2 < 4; j2++) {
          const float val = acc[f][t][j2] + qbp[j2];
          v0[f][j2] = val;
          ss = fmaf(val, val, ss);
        }
      }
      ss += __shfl_xor(ss, 16);
      ss += __shfl_xor(ss, 32);
      const float rn = scale / (sqrtf(ss) + 1e-12f);
      #pragma unroll
      for (int f = 0; f < 2; f++) {
        half4v hv;
        #pragma unroll
        for (int j2 = 0; j2 < 4; j2++) hv[j2] = (_Float16)(v0[f][j2] * rn);
        *(half4v*)(scr + (t*16 + r)*40 + f*16 + g*4) = hv;
      }
    }
    _Float16* dst = (part == 0 ? qh : kh) + slice;
    const int tl = lane >> 1;
    const int sel = (lane & 1) * 16;
    #pragma unroll
    for (int i8 = 0; i8 < 2; i8++) {
      const float4 vv = *(float4*)(scr + tl*40 + sel + i8*8);
      *(float4*)(dst + (size_t)(nbase + tl)*32 + sel + i8*8) = vv;
    }
  } else {
    float4 vb4[2];
    #pragma unroll
    for (int f = 0; f < 2; f++)
      vb4[f] = *(const float4*)(v_bias + hloc*32 + f*16 + g*4);
    #pragma unroll
    for (int t = 0; t < 2; t++) {
      #pragma unroll
      for (int f = 0; f < 2; f++) {
        const float* vbp = (const float*)&vb4[f];
        #pragma unroll
        for (int j2 = 0; j2 < 4; j2++)
          scr[(f*16 + g*4 + j2)*40 + t*16 + r] =
              (_Float16)(acc[f][t][j2] + vbp[j2]);
      }
    }
    _Float16* dst = vhT + slice;
    const int drow = lane >> 1;      // dim 0..31
    const int sel = (lane & 1) * 16;
    #pragma unroll
    for (int i8 = 0; i8 < 2; i8++) {
      const float4 vv = *(float4*)(scr + drow*40 + sel + i8*8);
      *(float4*)(dst + (size_t)drow*256 + nbase + sel + i8*8) = vv;
    }
  }
}

// ---------------------------------------------------------------------------
// MFMA attention (R13 config). 2 blocks per (window,head), 128 queries each;
// each wave owns 2 query tiles. XCD-swizzled. rpb via compact per-head LDS
// table in log2 domain. ah written in slice layout [bx][n][32].
// ---------------------------------------------------------------------------
__global__ __launch_bounds__(256) void attn_kernel(
    const _Float16* __restrict__ qh, const _Float16* __restrict__ kh,
    const _Float16* __restrict__ vhT, const float* __restrict__ Rtab,
    _Float16* __restrict__ ah)
{
  __shared__ half8v kf[16][64];
  __shared__ half4v vf[16][2][64];
  __shared__ float Rt[961];
  const int tid = threadIdx.x;
  const int hw = blockIdx.x;
  const int bid = (hw & 7) * 216 + (hw >> 3);   // XCD swizzle (1728 = 8*216)
  const int bx = bid >> 1;            // wb*6 + h
  const int qhalf = bid & 1;          // 128-query half
  const int wb = bx / 6;
  const int h  = bx - wb*6;
  const size_t slice = (size_t)bx * 8192;

  {
    const int j = tid >> 4, rr = tid & 15;
    const _Float16* src = kh + slice + (size_t)tid * 32;
    #pragma unroll
    for (int g4 = 0; g4 < 4; g4++)
      kf[j][16*g4 + rr] = *(const half8v*)(src + g4*8);
  }
  {
    const int mc = tid >> 4, rr = tid & 15;
    #pragma unroll
    for (int dt = 0; dt < 2; dt++) {
      const _Float16* src = vhT + slice + (size_t)(dt*16 + rr)*256 + mc*16;
      #pragma unroll
      for (int g4 = 0; g4 < 4; g4++)
        vf[mc][dt][16*g4 + rr] = *(const half4v*)(src + g4*4);
    }
  }
  for (int u = tid; u < 961; u += 256) Rt[u] = Rtab[h*961 + u];

  const int lane = tid & 63;
  const int wv   = tid >> 6;
  const int g    = lane >> 4;
  const int c    = lane & 15;
  const int n0   = qhalf*128 + wv*32 + c;   // first query row (tiles: +0, +16)
  const int nhi0 = qhalf*8 + wv*2;          // wave-uniform row-tile index

  const int wq = wb % 36;
  const int wy = wq / 6;
  const int wx = wq - wy*6;
  const bool lastY = (wy == 5);
  const float xm = ((wx == 5) && ((c >= 8) != (g >= 2))) ? -100000.f : 0.f;
  const int A3 = c - 4*g + 12;          // reversed-read base within R row

  half8v bq[2];
  #pragma unroll
  for (int ii = 0; ii < 2; ii++)
    bq[ii] = *(const half8v*)(qh + slice + (size_t)(n0 + ii*16)*32 + 8*g);

  __syncthreads();

  f32x4 o0[2], o1[2];
  float dsum[2];
  #pragma unroll
  for (int ii = 0; ii < 2; ii++) {
    o0[ii] = (f32x4){0.f,0.f,0.f,0.f};
    o1[ii] = (f32x4){0.f,0.f,0.f,0.f};
    dsum[ii] = 0.f;
  }

  #pragma unroll
  for (int j = 0; j < 16; j++) {
    const half8v kv = kf[j][lane];
    const half4v v0 = vf[j][0][lane];
    const half4v v1 = vf[j][1][lane];
    #pragma unroll
    for (int ii = 0; ii < 2; ii++) {
      const int nhi = nhi0 + ii;
      const float* rb = &Rt[(nhi - j + 15)*31 + A3];
      const float ym = (lastY && ((nhi >= 8) != (j >= 8))) ? -100000.f : 0.f;
      const float madd = xm + ym;
      f32x4 zero = {0.f,0.f,0.f,0.f};
      f32x4 s = mfma_k32(kv, bq[ii], zero);
      const float p0 = exp2fast(s[0] + rb[3] + madd);
      const float p1 = exp2fast(s[1] + rb[2] + madd);
      const float p2 = exp2fast(s[2] + rb[1] + madd);
      const float p3 = exp2fast(s[3] + rb[0] + madd);
      dsum[ii] += (p0 + p1) + (p2 + p3);
      half4v pf;
      pf[0]=(_Float16)p0; pf[1]=(_Float16)p1;
      pf[2]=(_Float16)p2; pf[3]=(_Float16)p3;
      o0[ii] = mfma_k16(v0, pf, o0[ii]);
      o1[ii] = mfma_k16(v1, pf, o1[ii]);
    }
  }

  #pragma unroll
  for (int ii = 0; ii < 2; ii++) {
    float d = dsum[ii] + __shfl_xor(dsum[ii], 16);
    d += __shfl_xor(d, 32);
    const float inv = 1.f / d;
    _Float16* obase = ah + slice + (size_t)(n0 + ii*16)*32 + 4*g;
    half4v h0, h1;
    #pragma unroll
    for (int j2 = 0; j2 < 4; j2++) {
      h0[j2] = (_Float16)(o0[ii][j2] * inv);
      h1[j2] = (_Float16)(o1[ii][j2] * inv);
    }
    *(half4v*)obase = h0;
    *(half4v*)(obase + 16) = h1;
  }
}

// ---------------------------------------------------------------------------
// proj_mfma: 64 tok x 64 feat tiles (LDS 51.2KB -> 3 blocks/CU), grid 1728
// with XCD-affinity swizzle (8 x 72 token-tiles x 3 feature tiles).
// C[out-feature][token] = Pw x A^T, fp16 MFMA, f32 scatter out.
// ---------------------------------------------------------------------------
__global__ __launch_bounds__(256) void proj_mfma(
    const _Float16* __restrict__ ah, const _Float16* __restrict__ ph,
    const float* __restrict__ pb, float* __restrict__ out)
{
  __shared__ _Float16 xs[64*200];
  __shared__ _Float16 wsm[64*200];
  const int tid = threadIdx.x;
  const int id = blockIdx.x;
  const int xcd = id & 7;
  const int local = id >> 3;            // 0..215
  const int lt = local / 3;             // 0..71
  const int ft = local - lt*3;          // 0..2
  const int tok0 = (xcd*72 + lt) * 64;
  const int feat0 = ft * 64;

  {
    const int wb2 = tok0 >> 8;
    const int nb0 = tok0 & 255;
    #pragma unroll
    for (int it = 0; it < 6; it++) {
      const int u = it*256 + tid;            // 16B units, 1536 total
      const int row = u / 24, uu = u - row*24;
      const int hh = uu >> 2;                // head of this 16B chunk
      const int dd = (uu & 3) * 8;           // dim offset within head
      const _Float16* src = ah + ((size_t)(wb2*6 + hh))*8192
                               + (size_t)(nb0 + row)*32 + dd;
      *(float4*)(xs + row*200 + uu*8) = *(const float4*)src;
    }
    const _Float16* src = ph + (size_t)feat0 * CC;
    #pragma unroll
    for (int it = 0; it < 6; it++) {
      const int u = it*256 + tid;
      const int row = u / 24, uu = u - row*24;
      *(float4*)(wsm + row*200 + uu*8) = *(const float4*)(src + u*8);
    }
  }
  __syncthreads();

  const int lane = tid & 63;
  const int wv = tid >> 6;
  const int g = lane >> 4;
  const int r = lane & 15;
  const int wf = (wv & 1) * 32;
  const int wt = (wv >> 1) * 32;

  f32x4 acc[2][2];
  #pragma unroll
  for (int f = 0; f < 2; f++)
    #pragma unroll
    for (int t = 0; t < 2; t++) acc[f][t] = (f32x4){0.f,0.f,0.f,0.f};

  const _Float16* wbase = wsm + (wf + r)*200 + g*8;
  const _Float16* xbase = xs + (wt + r)*200 + g*8;
  #pragma unroll
  for (int ks = 0; ks < 6; ks++) {
    half8v af[2], bf[2];
    #pragma unroll
    for (int f = 0; f < 2; f++) af[f] = *(const half8v*)(wbase + f*16*200 + ks*32);
    #pragma unroll
    for (int t = 0; t < 2; t++) bf[t] = *(const half8v*)(xbase + t*16*200 + ks*32);
    #pragma unroll
    for (int f = 0; f < 2; f++)
      #pragma unroll
      for (int t = 0; t < 2; t++)
        acc[f][t] = mfma_k32(af[f], bf[t], acc[f][t]);
  }

  const int nf0 = feat0 + wf + g*4;
  float4 pb4[2];
  pb4[0] = *(const float4*)(pb + nf0);
  pb4[1] = *(const float4*)(pb + nf0 + 16);
  #pragma unroll
  for (int t = 0; t < 2; t++) {
    const int tg = tok0 + wt + t*16 + r;
    const int wb2 = tg >> 8;
    const int n2 = tg & 255;
    const int b = wb2 / 36;
    const int wq = wb2 - b*36;
    const int wy = wq / 6;
    const int wx = wq - wy*6;
    const int iy = (wy*16 + (n2 >> 4) + 8) % 96;
    const int ix = (wx*16 + (n2 & 15) + 8) % 96;
    float* obase = out + (size_t)((b*96 + iy)*96 + ix)*CC + nf0;
    #pragma unroll
    for (int f = 0; f < 2; f++) {
      const float* pbp = (const float*)&pb4[f];
      *(float4*)(obase + f*16) = make_float4(
          acc[f][t][0] + pbp[0], acc[f][t][1] + pbp[1],
          acc[f][t][2] + pbp[2], acc[f][t][3] + pbp[3]);
    }
  }
}

extern "C" void kernel_launch(void* const* d_in, const int* in_sizes, int n_in,
                              void* d_out, int out_size, void* d_ws, size_t ws_size,
                              hipStream_t stream) {
  const float* x      = (const float*)d_in[0];
  const float* qkv_w  = (const float*)d_in[1];
  const float* q_bias = (const float*)d_in[2];
  const float* v_bias = (const float*)d_in[3];
  const float* ls     = (const float*)d_in[4];
  const float* cpb_w1 = (const float*)d_in[5];
  const float* cpb_b1 = (const float*)d_in[6];
  const float* cpb_w2 = (const float*)d_in[7];
  const float* proj_w = (const float*)d_in[8];
  const float* proj_b = (const float*)d_in[9];
  const float* tab    = (const float*)d_in[10];
  float* out = (float*)d_out;

  char* wsb = (char*)d_ws;
  _Float16* qh  = (_Float16*)(wsb);
  _Float16* kh  = (_Float16*)(wsb + 1*14155776);
  _Float16* vhT = (_Float16*)(wsb + 2*14155776);
  _Float16* ah  = (_Float16*)(wsb + 3*14155776);
  _Float16* xh  = (_Float16*)(wsb + 4*14155776);
  float* Rtab   = (float*)(wsb + 5*14155776);
  _Float16* wh  = (_Float16*)(wsb + 5*14155776 + 32768);
  _Float16* ph  = (_Float16*)(wsb + 5*14155776 + 32768 + 221184);

  cvt_cpb<<<7297, 256, 0, stream>>>(x, xh, tab, cpb_w1, cpb_b1, cpb_w2,
                                    ls, Rtab, qkv_w, proj_w, wh, ph);
  qkv_mfma<<<5184, 256, 0, stream>>>(xh, wh, q_bias, v_bias, ls,
                                     qh, kh, vhT);
  attn_kernel<<<1728, 256, 0, stream>>>(qh, kh, vhT, Rtab, ah);
  proj_mfma<<<1728, 256, 0, stream>>>(ah, ph, proj_b, out);
}

// Round 21
// 70.189 us; speedup vs baseline: 1.1030x; 1.0288x over previous
//
#include <hip/hip_runtime.h>

#define CC 192
#define LOG100 4.6051701859880914f
#define PSHIFT 11.0f   // softmax-invariant scale: keeps fp16 P out of subnormals
#define LOG2E  1.4426950408889634f

typedef _Float16 half8v __attribute__((ext_vector_type(8)));
typedef _Float16 half4v __attribute__((ext_vector_type(4)));
typedef float f32x4 __attribute__((ext_vector_type(4)));

static __device__ __forceinline__ f32x4 mfma_k32(half8v a, half8v b, f32x4 c) {
#if __has_builtin(__builtin_amdgcn_mfma_f32_16x16x32_f16)
  return __builtin_amdgcn_mfma_f32_16x16x32_f16(a, b, c, 0, 0, 0);
#else
  asm("v_mfma_f32_16x16x32_f16 %0, %1, %2, %0" : "+v"(c) : "v"(a), "v"(b));
  return c;
#endif
}
static __device__ __forceinline__ f32x4 mfma_k16(half4v a, half4v b, f32x4 c) {
#if __has_builtin(__builtin_amdgcn_mfma_f32_16x16x16f16)
  return __builtin_amdgcn_mfma_f32_16x16x16f16(a, b, c, 0, 0, 0);
#else
  asm("v_mfma_f32_16x16x16_f16 %0, %1, %2, %0" : "+v"(c) : "v"(a), "v"(b));
  return c;
#endif
}
static __device__ __forceinline__ float exp2fast(float x) {
#if __has_builtin(__builtin_amdgcn_exp2f)
  return __builtin_amdgcn_exp2f(x);
#else
  return exp2f(x);
#endif
}

// ---------------------------------------------------------------------------
// cvt_cpb: fused prepass.
//   Blocks [0,6912):     roll+window gather f32->fp16 (xh)
//   Blocks [6912,7153):  CPB MLP -> Rtab (4 entries/block, 1 per wave)
//   Blocks [7153,7297):  qkv_w + proj_w f32 -> fp16 (wh, ph)
// ---------------------------------------------------------------------------
__global__ __launch_bounds__(256) void cvt_cpb(
    const float* __restrict__ x, _Float16* __restrict__ xh,
    const float* __restrict__ tab, const float* __restrict__ w1,
    const float* __restrict__ b1, const float* __restrict__ w2,
    const float* __restrict__ ls, float* __restrict__ Rtab,
    const float* __restrict__ qkvw, const float* __restrict__ projw,
    _Float16* __restrict__ wh, _Float16* __restrict__ ph)
{
  if (blockIdx.x < 6912) {
    const int q = blockIdx.x * 256 + threadIdx.x;   // float4 units: 36864*48
    const int token = q / 48;
    const int c4 = q - token * 48;
    const int wb = token >> 8;
    const int n = token & 255;
    const int b = wb / 36;
    const int wq = wb - b * 36;
    const int wy = wq / 6;
    const int wx = wq - wy * 6;
    const int iy = (wy * 16 + (n >> 4) + 8) % 96;
    const int ix = (wx * 16 + (n & 15) + 8) % 96;
    const float4 v = *(const float4*)(x + (size_t)((b * 96 + iy) * 96 + ix) * CC + c4 * 4);
    half4v hv = {(_Float16)v.x, (_Float16)v.y, (_Float16)v.z, (_Float16)v.w};
    *(half4v*)(xh + (size_t)token * CC + c4 * 4) = hv;
    return;
  }
  if (blockIdx.x >= 7153) {
    const int q = (blockIdx.x - 7153) * 256 + threadIdx.x;  // 0..36863 float4 units
    float4 v;
    _Float16* dst;
    int off;
    if (q < 27648) { v = *(const float4*)(qkvw + q * 4); dst = wh; off = q * 4; }
    else { const int p2 = q - 27648; v = *(const float4*)(projw + p2 * 4); dst = ph; off = p2 * 4; }
    half4v hv = {(_Float16)v.x, (_Float16)v.y, (_Float16)v.z, (_Float16)v.w};
    *(half4v*)(dst + off) = hv;
    return;
  }
  const int p = (blockIdx.x - 6912) * 4 + (threadIdx.x >> 6);
  if (p >= 961) return;
  const int lane = threadIdx.x & 63;
  const float t0 = tab[p*2+0];
  const float t1 = tab[p*2+1];
  float a0=0.f,a1=0.f,a2=0.f,a3=0.f,a4=0.f,a5=0.f;
  for (int j = lane; j < 512; j += 64) {
    float hv = fmaxf(fmaf(t0, w1[2*j], fmaf(t1, w1[2*j+1], b1[j])), 0.f);
    a0 = fmaf(hv, w2[0*512+j], a0);
    a1 = fmaf(hv, w2[1*512+j], a1);
    a2 = fmaf(hv, w2[2*512+j], a2);
    a3 = fmaf(hv, w2[3*512+j], a3);
    a4 = fmaf(hv, w2[4*512+j], a4);
    a5 = fmaf(hv, w2[5*512+j], a5);
  }
  #pragma unroll
  for (int off = 32; off > 0; off >>= 1) {
    a0 += __shfl_down(a0, off);
    a1 += __shfl_down(a1, off);
    a2 += __shfl_down(a2, off);
    a3 += __shfl_down(a3, off);
    a4 += __shfl_down(a4, off);
    a5 += __shfl_down(a5, off);
  }
  if (lane == 0) {
    float av[6] = {a0, a1, a2, a3, a4, a5};
    #pragma unroll
    for (int h = 0; h < 6; h++) {
      const float rpb = 16.f / (1.f + __expf(-av[h]));
      const float bound = __expf(fminf(ls[h], LOG100)) + 16.f;
      Rtab[h*961 + p] = (rpb - bound + PSHIFT) * LOG2E;
    }
  }
}

// ---------------------------------------------------------------------------
// qkv_mfma: 64 tok x 64 feat tiles, 1D grid 5184 with XCD-affinity swizzle.
// Epilogue: bias + cosine-norm + log2e scale; qh/kh [n][d], v [d][n].
// ---------------------------------------------------------------------------
__global__ __launch_bounds__(256) void qkv_mfma(
    const _Float16* __restrict__ xh, const _Float16* __restrict__ wh,
    const float* __restrict__ q_bias, const float* __restrict__ v_bias,
    const float* __restrict__ ls,
    _Float16* __restrict__ qh, _Float16* __restrict__ kh,
    _Float16* __restrict__ vhT)
{
  __shared__ _Float16 xs[64*200];
  __shared__ _Float16 wsm[64*200];
  const int tid = threadIdx.x;
  const int id = blockIdx.x;
  const int xcd = id & 7;
  const int local = id >> 3;            // 0..647
  const int lt = local / 9;             // 0..71
  const int ft = local - lt*9;          // feature tile 0..8
  const int tok0 = (xcd*72 + lt) * 64;
  const int feat0 = ft * 64;

  // ---- stage x tile: contiguous fp16 copy ----
  {
    const _Float16* src = xh + (size_t)tok0 * CC;
    #pragma unroll
    for (int it = 0; it < 6; it++) {
      const int u = it*256 + tid;           // 16B units, 1536 total
      const int row = u / 24, uu = u - row*24;
      *(float4*)(xs + row*200 + uu*8) = *(const float4*)(src + u*8);
    }
  }
  // ---- stage w tile: contiguous fp16 copy ----
  {
    const _Float16* src = wh + (size_t)feat0 * CC;
    #pragma unroll
    for (int it = 0; it < 6; it++) {
      const int u = it*256 + tid;           // 1536 units
      const int row = u / 24, uu = u - row*24;
      *(float4*)(wsm + row*200 + uu*8) = *(const float4*)(src + u*8);
    }
  }
  __syncthreads();

  const int lane = tid & 63;
  const int wv = tid >> 6;
  const int g = lane >> 4;
  const int r = lane & 15;
  const int wf = (wv & 1) * 32;     // feature half
  const int wt = (wv >> 1) * 32;    // token half

  f32x4 acc[2][2];
  #pragma unroll
  for (int f = 0; f < 2; f++)
    #pragma unroll
    for (int t = 0; t < 2; t++) acc[f][t] = (f32x4){0.f,0.f,0.f,0.f};

  const _Float16* wbase = wsm + (wf + r)*200 + g*8;
  const _Float16* xbase = xs + (wt + r)*200 + g*8;
  #pragma unroll
  for (int ks = 0; ks < 6; ks++) {
    half8v af[2], bf[2];
    #pragma unroll
    for (int f = 0; f < 2; f++) af[f] = *(const half8v*)(wbase + f*16*200 + ks*32);
    #pragma unroll
    for (int t = 0; t < 2; t++) bf[t] = *(const half8v*)(xbase + t*16*200 + ks*32);
    #pragma unroll
    for (int f = 0; f < 2; f++)
      #pragma unroll
      for (int t = 0; t < 2; t++)
        acc[f][t] = mfma_k32(af[f], bf[t], acc[f][t]);
  }
  __syncthreads();    // tiles consumed; reuse xs as scratch

  const int part = ft / 3;                       // 0=q 1=k 2=v
  const int hloc = (ft - part*3) * 2 + (wf >> 5);     // head 0..5
  const int wbw  = tok0 >> 8;
  const int nbase = (tok0 & 255) + wt;
  const size_t slice = ((size_t)wbw * 6 + hloc) * 8192;
  _Float16* scr = xs + wv * 1280;

  if (part < 2) {
    float4 qb4[2];
    float scale = 1.f;
    if (part == 0) {
      #pragma unroll
      for (int f = 0; f < 2; f++)
        qb4[f] = *(const float4*)(q_bias + hloc*32 + f*16 + g*4);
      scale = __expf(fminf(ls[hloc], LOG100)) * LOG2E;   // exp2-domain softmax
    } else {
      qb4[0] = make_float4(0.f,0.f,0.f,0.f);
      qb4[1] = make_float4(0.f,0.f,0.f,0.f);
    }
    #pragma unroll
    for (int t = 0; t < 2; t++) {
      float v0[2][4];
      float ss = 0.f;
      #pragma unroll
      for (int f = 0; f < 2; f++) {
        const float* qbp = (const float*)&qb4[f];
        #pragma unroll
        for (int j2 = 0; j2 < 4; j2++) {
          const float val = acc[f][t][j2] + qbp[j2];
          v0[f][j2] = val;
          ss = fmaf(val, val, ss);
        }
      }
      ss += __shfl_xor(ss, 16);
      ss += __shfl_xor(ss, 32);
      const float rn = scale / (sqrtf(ss) + 1e-12f);
      #pragma unroll
      for (int f = 0; f < 2; f++) {
        half4v hv;
        #pragma unroll
        for (int j2 = 0; j2 < 4; j2++) hv[j2] = (_Float16)(v0[f][j2] * rn);
        *(half4v*)(scr + (t*16 + r)*40 + f*16 + g*4) = hv;
      }
    }
    _Float16* dst = (part == 0 ? qh : kh) + slice;
    const int tl = lane >> 1;
    const int sel = (lane & 1) * 16;
    #pragma unroll
    for (int i8 = 0; i8 < 2; i8++) {
      const float4 vv = *(float4*)(scr + tl*40 + sel + i8*8);
      *(float4*)(dst + (size_t)(nbase + tl)*32 + sel + i8*8) = vv;
    }
  } else {
    float4 vb4[2];
    #pragma unroll
    for (int f = 0; f < 2; f++)
      vb4[f] = *(const float4*)(v_bias + hloc*32 + f*16 + g*4);
    #pragma unroll
    for (int t = 0; t < 2; t++) {
      #pragma unroll
      for (int f = 0; f < 2; f++) {
        const float* vbp = (const float*)&vb4[f];
        #pragma unroll
        for (int j2 = 0; j2 < 4; j2++)
          scr[(f*16 + g*4 + j2)*40 + t*16 + r] =
              (_Float16)(acc[f][t][j2] + vbp[j2]);
      }
    }
    _Float16* dst = vhT + slice;
    const int drow = lane >> 1;      // dim 0..31
    const int sel = (lane & 1) * 16;
    #pragma unroll
    for (int i8 = 0; i8 < 2; i8++) {
      const float4 vv = *(float4*)(scr + drow*40 + sel + i8*8);
      *(float4*)(dst + (size_t)drow*256 + nbase + sel + i8*8) = vv;
    }
  }
}

// ---------------------------------------------------------------------------
// MFMA attention (R13 config + accumulator-init). 2 blocks per (window,head),
// 128 queries each; each wave owns 2 query tiles. rb+mask preloaded into the
// QK^T MFMA C-operand: removes 4 serial adds from the post-MFMA chain.
// XCD-swizzled. ah written in slice layout [bx][n][32].
// ---------------------------------------------------------------------------
__global__ __launch_bounds__(256) void attn_kernel(
    const _Float16* __restrict__ qh, const _Float16* __restrict__ kh,
    const _Float16* __restrict__ vhT, const float* __restrict__ Rtab,
    _Float16* __restrict__ ah)
{
  __shared__ half8v kf[16][64];
  __shared__ half4v vf[16][2][64];
  __shared__ float Rt[961];
  const int tid = threadIdx.x;
  const int hw = blockIdx.x;
  const int bid = (hw & 7) * 216 + (hw >> 3);   // XCD swizzle (1728 = 8*216)
  const int bx = bid >> 1;            // wb*6 + h
  const int qhalf = bid & 1;          // 128-query half
  const int wb = bx / 6;
  const int h  = bx - wb*6;
  const size_t slice = (size_t)bx * 8192;

  {
    const int j = tid >> 4, rr = tid & 15;
    const _Float16* src = kh + slice + (size_t)tid * 32;
    #pragma unroll
    for (int g4 = 0; g4 < 4; g4++)
      kf[j][16*g4 + rr] = *(const half8v*)(src + g4*8);
  }
  {
    const int mc = tid >> 4, rr = tid & 15;
    #pragma unroll
    for (int dt = 0; dt < 2; dt++) {
      const _Float16* src = vhT + slice + (size_t)(dt*16 + rr)*256 + mc*16;
      #pragma unroll
      for (int g4 = 0; g4 < 4; g4++)
        vf[mc][dt][16*g4 + rr] = *(const half4v*)(src + g4*4);
    }
  }
  for (int u = tid; u < 961; u += 256) Rt[u] = Rtab[h*961 + u];

  const int lane = tid & 63;
  const int wv   = tid >> 6;
  const int g    = lane >> 4;
  const int c    = lane & 15;
  const int n0   = qhalf*128 + wv*32 + c;   // first query row (tiles: +0, +16)
  const int nhi0 = qhalf*8 + wv*2;          // wave-uniform row-tile index

  const int wq = wb % 36;
  const int wy = wq / 6;
  const int wx = wq - wy*6;
  const bool lastY = (wy == 5);
  const float xm = ((wx == 5) && ((c >= 8) != (g >= 2))) ? -100000.f : 0.f;
  const int A3 = c - 4*g + 12;          // reversed-read base within R row

  half8v bq[2];
  #pragma unroll
  for (int ii = 0; ii < 2; ii++)
    bq[ii] = *(const half8v*)(qh + slice + (size_t)(n0 + ii*16)*32 + 8*g);

  __syncthreads();

  f32x4 o0[2], o1[2];
  float dsum[2];
  #pragma unroll
  for (int ii = 0; ii < 2; ii++) {
    o0[ii] = (f32x4){0.f,0.f,0.f,0.f};
    o1[ii] = (f32x4){0.f,0.f,0.f,0.f};
    dsum[ii] = 0.f;
  }

  #pragma unroll
  for (int j = 0; j < 16; j++) {
    const half8v kv = kf[j][lane];
    const half4v v0 = vf[j][0][lane];
    const half4v v1 = vf[j][1][lane];
    #pragma unroll
    for (int ii = 0; ii < 2; ii++) {
      const int nhi = nhi0 + ii;
      const float* rb = &Rt[(nhi - j + 15)*31 + A3];
      const float ym = (lastY && ((nhi >= 8) != (j >= 8))) ? -100000.f : 0.f;
      const float madd = xm + ym;
      // rb+mask in the C-operand: adds overlap the MFMA instead of chaining
      f32x4 cinit = {rb[3] + madd, rb[2] + madd, rb[1] + madd, rb[0] + madd};
      f32x4 s = mfma_k32(kv, bq[ii], cinit);
      const float p0 = exp2fast(s[0]);
      const float p1 = exp2fast(s[1]);
      const float p2 = exp2fast(s[2]);
      const float p3 = exp2fast(s[3]);
      dsum[ii] += (p0 + p1) + (p2 + p3);
      half4v pf;
      pf[0]=(_Float16)p0; pf[1]=(_Float16)p1;
      pf[2]=(_Float16)p2; pf[3]=(_Float16)p3;
      o0[ii] = mfma_k16(v0, pf, o0[ii]);
      o1[ii] = mfma_k16(v1, pf, o1[ii]);
    }
  }

  #pragma unroll
  for (int ii = 0; ii < 2; ii++) {
    float d = dsum[ii] + __shfl_xor(dsum[ii], 16);
    d += __shfl_xor(d, 32);
    const float inv = 1.f / d;
    _Float16* obase = ah + slice + (size_t)(n0 + ii*16)*32 + 4*g;
    half4v h0, h1;
    #pragma unroll
    for (int j2 = 0; j2 < 4; j2++) {
      h0[j2] = (_Float16)(o0[ii][j2] * inv);
      h1[j2] = (_Float16)(o1[ii][j2] * inv);
    }
    *(half4v*)obase = h0;
    *(half4v*)(obase + 16) = h1;
  }
}

// ---------------------------------------------------------------------------
// proj_mfma: 64 tok x 64 feat tiles (LDS 51.2KB -> 3 blocks/CU), grid 1728
// with XCD-affinity swizzle (8 x 72 token-tiles x 3 feature tiles).
// C[out-feature][token] = Pw x A^T, fp16 MFMA, f32 scatter out.
// ---------------------------------------------------------------------------
__global__ __launch_bounds__(256) void proj_mfma(
    const _Float16* __restrict__ ah, const _Float16* __restrict__ ph,
    const float* __restrict__ pb, float* __restrict__ out)
{
  __shared__ _Float16 xs[64*200];
  __shared__ _Float16 wsm[64*200];
  const int tid = threadIdx.x;
  const int id = blockIdx.x;
  const int xcd = id & 7;
  const int local = id >> 3;            // 0..215
  const int lt = local / 3;             // 0..71
  const int ft = local - lt*3;          // 0..2
  const int tok0 = (xcd*72 + lt) * 64;
  const int feat0 = ft * 64;

  {
    const int wb2 = tok0 >> 8;
    const int nb0 = tok0 & 255;
    #pragma unroll
    for (int it = 0; it < 6; it++) {
      const int u = it*256 + tid;            // 16B units, 1536 total
      const int row = u / 24, uu = u - row*24;
      const int hh = uu >> 2;                // head of this 16B chunk
      const int dd = (uu & 3) * 8;           // dim offset within head
      const _Float16* src = ah + ((size_t)(wb2*6 + hh))*8192
                               + (size_t)(nb0 + row)*32 + dd;
      *(float4*)(xs + row*200 + uu*8) = *(const float4*)src;
    }
    const _Float16* src = ph + (size_t)feat0 * CC;
    #pragma unroll
    for (int it = 0; it < 6; it++) {
      const int u = it*256 + tid;
      const int row = u / 24, uu = u - row*24;
      *(float4*)(wsm + row*200 + uu*8) = *(const float4*)(src + u*8);
    }
  }
  __syncthreads();

  const int lane = tid & 63;
  const int wv = tid >> 6;
  const int g = lane >> 4;
  const int r = lane & 15;
  const int wf = (wv & 1) * 32;
  const int wt = (wv >> 1) * 32;

  f32x4 acc[2][2];
  #pragma unroll
  for (int f = 0; f < 2; f++)
    #pragma unroll
    for (int t = 0; t < 2; t++) acc[f][t] = (f32x4){0.f,0.f,0.f,0.f};

  const _Float16* wbase = wsm + (wf + r)*200 + g*8;
  const _Float16* xbase = xs + (wt + r)*200 + g*8;
  #pragma unroll
  for (int ks = 0; ks < 6; ks++) {
    half8v af[2], bf[2];
    #pragma unroll
    for (int f = 0; f < 2; f++) af[f] = *(const half8v*)(wbase + f*16*200 + ks*32);
    #pragma unroll
    for (int t = 0; t < 2; t++) bf[t] = *(const half8v*)(xbase + t*16*200 + ks*32);
    #pragma unroll
    for (int f = 0; f < 2; f++)
      #pragma unroll
      for (int t = 0; t < 2; t++)
        acc[f][t] = mfma_k32(af[f], bf[t], acc[f][t]);
  }

  const int nf0 = feat0 + wf + g*4;
  float4 pb4[2];
  pb4[0] = *(const float4*)(pb + nf0);
  pb4[1] = *(const float4*)(pb + nf0 + 16);
  #pragma unroll
  for (int t = 0; t < 2; t++) {
    const int tg = tok0 + wt + t*16 + r;
    const int wb2 = tg >> 8;
    const int n2 = tg & 255;
    const int b = wb2 / 36;
    const int wq = wb2 - b*36;
    const int wy = wq / 6;
    const int wx = wq - wy*6;
    const int iy = (wy*16 + (n2 >> 4) + 8) % 96;
    const int ix = (wx*16 + (n2 & 15) + 8) % 96;
    float* obase = out + (size_t)((b*96 + iy)*96 + ix)*CC + nf0;
    #pragma unroll
    for (int f = 0; f < 2; f++) {
      const float* pbp = (const float*)&pb4[f];
      *(float4*)(obase + f*16) = make_float4(
          acc[f][t][0] + pbp[0], acc[f][t][1] + pbp[1],
          acc[f][t][2] + pbp[2], acc[f][t][3] + pbp[3]);
    }
  }
}

extern "C" void kernel_launch(void* const* d_in, const int* in_sizes, int n_in,
                              void* d_out, int out_size, void* d_ws, size_t ws_size,
                              hipStream_t stream) {
  const float* x      = (const float*)d_in[0];
  const float* qkv_w  = (const float*)d_in[1];
  const float* q_bias = (const float*)d_in[2];
  const float* v_bias = (const float*)d_in[3];
  const float* ls     = (const float*)d_in[4];
  const float* cpb_w1 = (const float*)d_in[5];
  const float* cpb_b1 = (const float*)d_in[6];
  const float* cpb_w2 = (const float*)d_in[7];
  const float* proj_w = (const float*)d_in[8];
  const float* proj_b = (const float*)d_in[9];
  const float* tab    = (const float*)d_in[10];
  float* out = (float*)d_out;

  char* wsb = (char*)d_ws;
  _Float16* qh  = (_Float16*)(wsb);
  _Float16* kh  = (_Float16*)(wsb + 1*14155776);
  _Float16* vhT = (_Float16*)(wsb + 2*14155776);
  _Float16* ah  = (_Float16*)(wsb + 3*14155776);
  _Float16* xh  = (_Float16*)(wsb + 4*14155776);
  float* Rtab   = (float*)(wsb + 5*14155776);
  _Float16* wh  = (_Float16*)(wsb + 5*14155776 + 32768);
  _Float16* ph  = (_Float16*)(wsb + 5*14155776 + 32768 + 221184);

  cvt_cpb<<<7297, 256, 0, stream>>>(x, xh, tab, cpb_w1, cpb_b1, cpb_w2,
                                    ls, Rtab, qkv_w, proj_w, wh, ph);
  qkv_mfma<<<5184, 256, 0, stream>>>(xh, wh, q_bias, v_bias, ls,
                                     qh, kh, vhT);
  attn_kernel<<<1728, 256, 0, stream>>>(qh, kh, vhT, Rtab, ah);
  proj_mfma<<<1728, 256, 0, stream>>>(ah, ph, proj_b, out);
}

// Round 22
// 67.975 us; speedup vs baseline: 1.1389x; 1.0326x over previous
//
#include <hip/hip_runtime.h>

#define CC 192
#define LOG100 4.6051701859880914f
#define PSHIFT 11.0f   // softmax-invariant scale: keeps fp16 P out of subnormals
#define LOG2E  1.4426950408889634f

typedef _Float16 half8v __attribute__((ext_vector_type(8)));
typedef _Float16 half4v __attribute__((ext_vector_type(4)));
typedef float f32x4 __attribute__((ext_vector_type(4)));

static __device__ __forceinline__ f32x4 mfma_k32(half8v a, half8v b, f32x4 c) {
#if __has_builtin(__builtin_amdgcn_mfma_f32_16x16x32_f16)
  return __builtin_amdgcn_mfma_f32_16x16x32_f16(a, b, c, 0, 0, 0);
#else
  asm("v_mfma_f32_16x16x32_f16 %0, %1, %2, %0" : "+v"(c) : "v"(a), "v"(b));
  return c;
#endif
}
static __device__ __forceinline__ f32x4 mfma_k16(half4v a, half4v b, f32x4 c) {
#if __has_builtin(__builtin_amdgcn_mfma_f32_16x16x16f16)
  return __builtin_amdgcn_mfma_f32_16x16x16f16(a, b, c, 0, 0, 0);
#else
  asm("v_mfma_f32_16x16x16_f16 %0, %1, %2, %0" : "+v"(c) : "v"(a), "v"(b));
  return c;
#endif
}
static __device__ __forceinline__ float exp2fast(float x) {
#if __has_builtin(__builtin_amdgcn_exp2f)
  return __builtin_amdgcn_exp2f(x);
#else
  return exp2f(x);
#endif
}
static __device__ __forceinline__ half8v cvt8(const float* p) {
  const float4 a = *(const float4*)p;
  const float4 b = *(const float4*)(p + 4);
  half8v h;
  h[0]=(_Float16)a.x; h[1]=(_Float16)a.y; h[2]=(_Float16)a.z; h[3]=(_Float16)a.w;
  h[4]=(_Float16)b.x; h[5]=(_Float16)b.y; h[6]=(_Float16)b.z; h[7]=(_Float16)b.w;
  return h;
}

// ---------------------------------------------------------------------------
// cvt_cpb: fused prepass.
//   Blocks [0,6912):     roll+window gather f32->fp16 (xh)
//   Blocks [6912,7153):  CPB MLP -> Rtab (4 entries/block, 1 per wave)
//   Blocks [7153,7243):  qkv_w -> fragment-order table wfrag (13824 units);
//                        proj_w -> fp16 ph (9216 float4 units)
// wfrag layout: idx = (ft*6+ks)*4 + wf2*2 + f; halves off = idx*512 + lane*8
//   covers W row = ft*64 + wf2*32 + f*16 + (lane&15), col = ks*32 + (lane>>4)*8
// ---------------------------------------------------------------------------
__global__ __launch_bounds__(256) void cvt_cpb(
    const float* __restrict__ x, _Float16* __restrict__ xh,
    const float* __restrict__ tab, const float* __restrict__ w1,
    const float* __restrict__ b1, const float* __restrict__ w2,
    const float* __restrict__ ls, float* __restrict__ Rtab,
    const float* __restrict__ qkvw, const float* __restrict__ projw,
    _Float16* __restrict__ wfrag, _Float16* __restrict__ ph)
{
  if (blockIdx.x < 6912) {
    const int q = blockIdx.x * 256 + threadIdx.x;   // float4 units: 36864*48
    const int token = q / 48;
    const int c4 = q - token * 48;
    const int wb = token >> 8;
    const int n = token & 255;
    const int b = wb / 36;
    const int wq = wb - b * 36;
    const int wy = wq / 6;
    const int wx = wq - wy * 6;
    const int iy = (wy * 16 + (n >> 4) + 8) % 96;
    const int ix = (wx * 16 + (n & 15) + 8) % 96;
    const float4 v = *(const float4*)(x + (size_t)((b * 96 + iy) * 96 + ix) * CC + c4 * 4);
    half4v hv = {(_Float16)v.x, (_Float16)v.y, (_Float16)v.z, (_Float16)v.w};
    *(half4v*)(xh + (size_t)token * CC + c4 * 4) = hv;
    return;
  }
  if (blockIdx.x >= 7153) {
    const int u = (blockIdx.x - 7153) * 256 + threadIdx.x;
    if (u < 13824) {                      // qkv fragment table (16B units)
      const int lane = u & 63;
      const int f = (u >> 6) & 1;
      const int wf2 = (u >> 7) & 1;
      const int rem = u >> 8;             // 0..53
      const int ks = rem % 6;
      const int ft2 = rem / 6;            // 0..8
      const int row = ft2*64 + wf2*32 + f*16 + (lane & 15);
      const int col = ks*32 + (lane >> 4)*8;
      *(half8v*)(wfrag + (size_t)u*8) = cvt8(qkvw + (size_t)row*CC + col);
    } else {
      const int q = u - 13824;            // proj float4 units 0..9215
      if (q < 9216) {
        const float4 v = *(const float4*)(projw + q * 4);
        half4v hv = {(_Float16)v.x, (_Float16)v.y, (_Float16)v.z, (_Float16)v.w};
        *(half4v*)(ph + q * 4) = hv;
      }
    }
    return;
  }
  const int p = (blockIdx.x - 6912) * 4 + (threadIdx.x >> 6);
  if (p >= 961) return;
  const int lane = threadIdx.x & 63;
  const float t0 = tab[p*2+0];
  const float t1 = tab[p*2+1];
  float a0=0.f,a1=0.f,a2=0.f,a3=0.f,a4=0.f,a5=0.f;
  for (int j = lane; j < 512; j += 64) {
    float hv = fmaxf(fmaf(t0, w1[2*j], fmaf(t1, w1[2*j+1], b1[j])), 0.f);
    a0 = fmaf(hv, w2[0*512+j], a0);
    a1 = fmaf(hv, w2[1*512+j], a1);
    a2 = fmaf(hv, w2[2*512+j], a2);
    a3 = fmaf(hv, w2[3*512+j], a3);
    a4 = fmaf(hv, w2[4*512+j], a4);
    a5 = fmaf(hv, w2[5*512+j], a5);
  }
  #pragma unroll
  for (int off = 32; off > 0; off >>= 1) {
    a0 += __shfl_down(a0, off);
    a1 += __shfl_down(a1, off);
    a2 += __shfl_down(a2, off);
    a3 += __shfl_down(a3, off);
    a4 += __shfl_down(a4, off);
    a5 += __shfl_down(a5, off);
  }
  if (lane == 0) {
    float av[6] = {a0, a1, a2, a3, a4, a5};
    #pragma unroll
    for (int h = 0; h < 6; h++) {
      const float rpb = 16.f / (1.f + __expf(-av[h]));
      const float bound = __expf(fminf(ls[h], LOG100)) + 16.f;
      Rtab[h*961 + p] = (rpb - bound + PSHIFT) * LOG2E;
    }
  }
}

// ---------------------------------------------------------------------------
// qkv_mfma: 64 tok x 64 feat tiles, 1D grid 5184 with XCD-affinity swizzle.
// W read as pre-permuted fragments straight from global (coalesced 16B/lane,
// L2-resident 221KB table) -> NO W LDS staging; LDS 25.6KB -> 6 blocks/CU.
// Epilogue: bias + cosine-norm + log2e scale; qh/kh [n][d], v [d][n].
// ---------------------------------------------------------------------------
__global__ __launch_bounds__(256) void qkv_mfma(
    const _Float16* __restrict__ xh, const _Float16* __restrict__ wfrag,
    const float* __restrict__ q_bias, const float* __restrict__ v_bias,
    const float* __restrict__ ls,
    _Float16* __restrict__ qh, _Float16* __restrict__ kh,
    _Float16* __restrict__ vhT)
{
  __shared__ _Float16 xs[64*200];
  const int tid = threadIdx.x;
  const int id = blockIdx.x;
  const int xcd = id & 7;
  const int local = id >> 3;            // 0..647
  const int lt = local / 9;             // 0..71
  const int ft = local - lt*9;          // feature tile 0..8
  const int tok0 = (xcd*72 + lt) * 64;

  // ---- stage x tile: contiguous fp16 copy ----
  {
    const _Float16* src = xh + (size_t)tok0 * CC;
    #pragma unroll
    for (int it = 0; it < 6; it++) {
      const int u = it*256 + tid;           // 16B units, 1536 total
      const int row = u / 24, uu = u - row*24;
      *(float4*)(xs + row*200 + uu*8) = *(const float4*)(src + u*8);
    }
  }

  const int lane = tid & 63;
  const int wv = tid >> 6;
  const int g = lane >> 4;
  const int r = lane & 15;
  const int wf2 = wv & 1;           // feature half select
  const int wf = wf2 * 32;
  const int wt = (wv >> 1) * 32;    // token half

  // W fragment base: idx = (ft*6+ks)*4 + wf2*2 + f; halves = idx*512 + lane*8
  const _Float16* wbaseg = wfrag + ((size_t)(ft*6)*4 + wf2*2)*512 + lane*8;

  __syncthreads();

  f32x4 acc[2][2];
  #pragma unroll
  for (int f = 0; f < 2; f++)
    #pragma unroll
    for (int t = 0; t < 2; t++) acc[f][t] = (f32x4){0.f,0.f,0.f,0.f};

  const _Float16* xbase = xs + (wt + r)*200 + g*8;
  #pragma unroll
  for (int ks = 0; ks < 6; ks++) {
    half8v af[2], bf[2];
    af[0] = *(const half8v*)(wbaseg + ks*2048);
    af[1] = *(const half8v*)(wbaseg + ks*2048 + 512);
    #pragma unroll
    for (int t = 0; t < 2; t++) bf[t] = *(const half8v*)(xbase + t*16*200 + ks*32);
    #pragma unroll
    for (int f = 0; f < 2; f++)
      #pragma unroll
      for (int t = 0; t < 2; t++)
        acc[f][t] = mfma_k32(af[f], bf[t], acc[f][t]);
  }
  __syncthreads();    // tiles consumed; reuse xs as scratch

  const int part = ft / 3;                       // 0=q 1=k 2=v
  const int hloc = (ft - part*3) * 2 + (wf >> 5);     // head 0..5
  const int wbw  = tok0 >> 8;
  const int nbase = (tok0 & 255) + wt;
  const size_t slice = ((size_t)wbw * 6 + hloc) * 8192;
  _Float16* scr = xs + wv * 1280;

  if (part < 2) {
    float4 qb4[2];
    float scale = 1.f;
    if (part == 0) {
      #pragma unroll
      for (int f = 0; f < 2; f++)
        qb4[f] = *(const float4*)(q_bias + hloc*32 + f*16 + g*4);
      scale = __expf(fminf(ls[hloc], LOG100)) * LOG2E;   // exp2-domain softmax
    } else {
      qb4[0] = make_float4(0.f,0.f,0.f,0.f);
      qb4[1] = make_float4(0.f,0.f,0.f,0.f);
    }
    #pragma unroll
    for (int t = 0; t < 2; t++) {
      float v0[2][4];
      float ss = 0.f;
      #pragma unroll
      for (int f = 0; f < 2; f++) {
        const float* qbp = (const float*)&qb4[f];
        #pragma unroll
        for (int j2 = 0; j2 < 4; j2++) {
          const float val = acc[f][t][j2] + qbp[j2];
          v0[f][j2] = val;
          ss = fmaf(val, val, ss);
        }
      }
      ss += __shfl_xor(ss, 16);
      ss += __shfl_xor(ss, 32);
      const float rn = scale / (sqrtf(ss) + 1e-12f);
      #pragma unroll
      for (int f = 0; f < 2; f++) {
        half4v hv;
        #pragma unroll
        for (int j2 = 0; j2 < 4; j2++) hv[j2] = (_Float16)(v0[f][j2] * rn);
        *(half4v*)(scr + (t*16 + r)*40 + f*16 + g*4) = hv;
      }
    }
    _Float16* dst = (part == 0 ? qh : kh) + slice;
    const int tl = lane >> 1;
    const int sel = (lane & 1) * 16;
    #pragma unroll
    for (int i8 = 0; i8 < 2; i8++) {
      const float4 vv = *(float4*)(scr + tl*40 + sel + i8*8);
      *(float4*)(dst + (size_t)(nbase + tl)*32 + sel + i8*8) = vv;
    }
  } else {
    float4 vb4[2];
    #pragma unroll
    for (int f = 0; f < 2; f++)
      vb4[f] = *(const float4*)(v_bias + hloc*32 + f*16 + g*4);
    #pragma unroll
    for (int t = 0; t < 2; t++) {
      #pragma unroll
      for (int f = 0; f < 2; f++) {
        const float* vbp = (const float*)&vb4[f];
        #pragma unroll
        for (int j2 = 0; j2 < 4; j2++)
          scr[(f*16 + g*4 + j2)*40 + t*16 + r] =
              (_Float16)(acc[f][t][j2] + vbp[j2]);
      }
    }
    _Float16* dst = vhT + slice;
    const int drow = lane >> 1;      // dim 0..31
    const int sel = (lane & 1) * 16;
    #pragma unroll
    for (int i8 = 0; i8 < 2; i8++) {
      const float4 vv = *(float4*)(scr + drow*40 + sel + i8*8);
      *(float4*)(dst + (size_t)drow*256 + nbase + sel + i8*8) = vv;
    }
  }
}

// ---------------------------------------------------------------------------
// MFMA attention (R21 config: accumulator-init). 2 blocks per (window,head),
// 128 queries each; each wave owns 2 query tiles. XCD-swizzled.
// ah written in slice layout [bx][n][32].
// ---------------------------------------------------------------------------
__global__ __launch_bounds__(256) void attn_kernel(
    const _Float16* __restrict__ qh, const _Float16* __restrict__ kh,
    const _Float16* __restrict__ vhT, const float* __restrict__ Rtab,
    _Float16* __restrict__ ah)
{
  __shared__ half8v kf[16][64];
  __shared__ half4v vf[16][2][64];
  __shared__ float Rt[961];
  const int tid = threadIdx.x;
  const int hw = blockIdx.x;
  const int bid = (hw & 7) * 216 + (hw >> 3);   // XCD swizzle (1728 = 8*216)
  const int bx = bid >> 1;            // wb*6 + h
  const int qhalf = bid & 1;          // 128-query half
  const int wb = bx / 6;
  const int h  = bx - wb*6;
  const size_t slice = (size_t)bx * 8192;

  {
    const int j = tid >> 4, rr = tid & 15;
    const _Float16* src = kh + slice + (size_t)tid * 32;
    #pragma unroll
    for (int g4 = 0; g4 < 4; g4++)
      kf[j][16*g4 + rr] = *(const half8v*)(src + g4*8);
  }
  {
    const int mc = tid >> 4, rr = tid & 15;
    #pragma unroll
    for (int dt = 0; dt < 2; dt++) {
      const _Float16* src = vhT + slice + (size_t)(dt*16 + rr)*256 + mc*16;
      #pragma unroll
      for (int g4 = 0; g4 < 4; g4++)
        vf[mc][dt][16*g4 + rr] = *(const half4v*)(src + g4*4);
    }
  }
  for (int u = tid; u < 961; u += 256) Rt[u] = Rtab[h*961 + u];

  const int lane = tid & 63;
  const int wv   = tid >> 6;
  const int g    = lane >> 4;
  const int c    = lane & 15;
  const int n0   = qhalf*128 + wv*32 + c;   // first query row (tiles: +0, +16)
  const int nhi0 = qhalf*8 + wv*2;          // wave-uniform row-tile index

  const int wq = wb % 36;
  const int wy = wq / 6;
  const int wx = wq - wy*6;
  const bool lastY = (wy == 5);
  const float xm = ((wx == 5) && ((c >= 8) != (g >= 2))) ? -100000.f : 0.f;
  const int A3 = c - 4*g + 12;          // reversed-read base within R row

  half8v bq[2];
  #pragma unroll
  for (int ii = 0; ii < 2; ii++)
    bq[ii] = *(const half8v*)(qh + slice + (size_t)(n0 + ii*16)*32 + 8*g);

  __syncthreads();

  f32x4 o0[2], o1[2];
  float dsum[2];
  #pragma unroll
  for (int ii = 0; ii < 2; ii++) {
    o0[ii] = (f32x4){0.f,0.f,0.f,0.f};
    o1[ii] = (f32x4){0.f,0.f,0.f,0.f};
    dsum[ii] = 0.f;
  }

  #pragma unroll
  for (int j = 0; j < 16; j++) {
    const half8v kv = kf[j][lane];
    const half4v v0 = vf[j][0][lane];
    const half4v v1 = vf[j][1][lane];
    #pragma unroll
    for (int ii = 0; ii < 2; ii++) {
      const int nhi = nhi0 + ii;
      const float* rb = &Rt[(nhi - j + 15)*31 + A3];
      const float ym = (lastY && ((nhi >= 8) != (j >= 8))) ? -100000.f : 0.f;
      const float madd = xm + ym;
      // rb+mask in the C-operand: adds overlap the MFMA instead of chaining
      f32x4 cinit = {rb[3] + madd, rb[2] + madd, rb[1] + madd, rb[0] + madd};
      f32x4 s = mfma_k32(kv, bq[ii], cinit);
      const float p0 = exp2fast(s[0]);
      const float p1 = exp2fast(s[1]);
      const float p2 = exp2fast(s[2]);
      const float p3 = exp2fast(s[3]);
      dsum[ii] += (p0 + p1) + (p2 + p3);
      half4v pf;
      pf[0]=(_Float16)p0; pf[1]=(_Float16)p1;
      pf[2]=(_Float16)p2; pf[3]=(_Float16)p3;
      o0[ii] = mfma_k16(v0, pf, o0[ii]);
      o1[ii] = mfma_k16(v1, pf, o1[ii]);
    }
  }

  #pragma unroll
  for (int ii = 0; ii < 2; ii++) {
    float d = dsum[ii] + __shfl_xor(dsum[ii], 16);
    d += __shfl_xor(d, 32);
    const float inv = 1.f / d;
    _Float16* obase = ah + slice + (size_t)(n0 + ii*16)*32 + 4*g;
    half4v h0, h1;
    #pragma unroll
    for (int j2 = 0; j2 < 4; j2++) {
      h0[j2] = (_Float16)(o0[ii][j2] * inv);
      h1[j2] = (_Float16)(o1[ii][j2] * inv);
    }
    *(half4v*)obase = h0;
    *(half4v*)(obase + 16) = h1;
  }
}

// ---------------------------------------------------------------------------
// proj_mfma: 64 tok x 64 feat tiles (LDS 51.2KB -> 3 blocks/CU), grid 1728
// with XCD-affinity swizzle (8 x 72 token-tiles x 3 feature tiles).
// C[out-feature][token] = Pw x A^T, fp16 MFMA, f32 scatter out.
// ---------------------------------------------------------------------------
__global__ __launch_bounds__(256) void proj_mfma(
    const _Float16* __restrict__ ah, const _Float16* __restrict__ ph,
    const float* __restrict__ pb, float* __restrict__ out)
{
  __shared__ _Float16 xs[64*200];
  __shared__ _Float16 wsm[64*200];
  const int tid = threadIdx.x;
  const int id = blockIdx.x;
  const int xcd = id & 7;
  const int local = id >> 3;            // 0..215
  const int lt = local / 3;             // 0..71
  const int ft = local - lt*3;          // 0..2
  const int tok0 = (xcd*72 + lt) * 64;
  const int feat0 = ft * 64;

  {
    const int wb2 = tok0 >> 8;
    const int nb0 = tok0 & 255;
    #pragma unroll
    for (int it = 0; it < 6; it++) {
      const int u = it*256 + tid;            // 16B units, 1536 total
      const int row = u / 24, uu = u - row*24;
      const int hh = uu >> 2;                // head of this 16B chunk
      const int dd = (uu & 3) * 8;           // dim offset within head
      const _Float16* src = ah + ((size_t)(wb2*6 + hh))*8192
                               + (size_t)(nb0 + row)*32 + dd;
      *(float4*)(xs + row*200 + uu*8) = *(const float4*)src;
    }
    const _Float16* src = ph + (size_t)feat0 * CC;
    #pragma unroll
    for (int it = 0; it < 6; it++) {
      const int u = it*256 + tid;
      const int row = u / 24, uu = u - row*24;
      *(float4*)(wsm + row*200 + uu*8) = *(const float4*)(src + u*8);
    }
  }
  __syncthreads();

  const int lane = tid & 63;
  const int wv = tid >> 6;
  const int g = lane >> 4;
  const int r = lane & 15;
  const int wf = (wv & 1) * 32;
  const int wt = (wv >> 1) * 32;

  f32x4 acc[2][2];
  #pragma unroll
  for (int f = 0; f < 2; f++)
    #pragma unroll
    for (int t = 0; t < 2; t++) acc[f][t] = (f32x4){0.f,0.f,0.f,0.f};

  const _Float16* wbase = wsm + (wf + r)*200 + g*8;
  const _Float16* xbase = xs + (wt + r)*200 + g*8;
  #pragma unroll
  for (int ks = 0; ks < 6; ks++) {
    half8v af[2], bf[2];
    #pragma unroll
    for (int f = 0; f < 2; f++) af[f] = *(const half8v*)(wbase + f*16*200 + ks*32);
    #pragma unroll
    for (int t = 0; t < 2; t++) bf[t] = *(const half8v*)(xbase + t*16*200 + ks*32);
    #pragma unroll
    for (int f = 0; f < 2; f++)
      #pragma unroll
      for (int t = 0; t < 2; t++)
        acc[f][t] = mfma_k32(af[f], bf[t], acc[f][t]);
  }

  const int nf0 = feat0 + wf + g*4;
  float4 pb4[2];
  pb4[0] = *(const float4*)(pb + nf0);
  pb4[1] = *(const float4*)(pb + nf0 + 16);
  #pragma unroll
  for (int t = 0; t < 2; t++) {
    const int tg = tok0 + wt + t*16 + r;
    const int wb2 = tg >> 8;
    const int n2 = tg & 255;
    const int b = wb2 / 36;
    const int wq = wb2 - b*36;
    const int wy = wq / 6;
    const int wx = wq - wy*6;
    const int iy = (wy*16 + (n2 >> 4) + 8) % 96;
    const int ix = (wx*16 + (n2 & 15) + 8) % 96;
    float* obase = out + (size_t)((b*96 + iy)*96 + ix)*CC + nf0;
    #pragma unroll
    for (int f = 0; f < 2; f++) {
      const float* pbp = (const float*)&pb4[f];
      *(float4*)(obase + f*16) = make_float4(
          acc[f][t][0] + pbp[0], acc[f][t][1] + pbp[1],
          acc[f][t][2] + pbp[2], acc[f][t][3] + pbp[3]);
    }
  }
}

extern "C" void kernel_launch(void* const* d_in, const int* in_sizes, int n_in,
                              void* d_out, int out_size, void* d_ws, size_t ws_size,
                              hipStream_t stream) {
  const float* x      = (const float*)d_in[0];
  const float* qkv_w  = (const float*)d_in[1];
  const float* q_bias = (const float*)d_in[2];
  const float* v_bias = (const float*)d_in[3];
  const float* ls     = (const float*)d_in[4];
  const float* cpb_w1 = (const float*)d_in[5];
  const float* cpb_b1 = (const float*)d_in[6];
  const float* cpb_w2 = (const float*)d_in[7];
  const float* proj_w = (const float*)d_in[8];
  const float* proj_b = (const float*)d_in[9];
  const float* tab    = (const float*)d_in[10];
  float* out = (float*)d_out;

  char* wsb = (char*)d_ws;
  _Float16* qh    = (_Float16*)(wsb);
  _Float16* kh    = (_Float16*)(wsb + 1*14155776);
  _Float16* vhT   = (_Float16*)(wsb + 2*14155776);
  _Float16* ah    = (_Float16*)(wsb + 3*14155776);
  _Float16* xh    = (_Float16*)(wsb + 4*14155776);
  float* Rtab     = (float*)(wsb + 5*14155776);
  _Float16* wfrag = (_Float16*)(wsb + 5*14155776 + 32768);
  _Float16* ph    = (_Float16*)(wsb + 5*14155776 + 32768 + 221184);

  cvt_cpb<<<7243, 256, 0, stream>>>(x, xh, tab, cpb_w1, cpb_b1, cpb_w2,
                                    ls, Rtab, qkv_w, proj_w, wfrag, ph);
  qkv_mfma<<<5184, 256, 0, stream>>>(xh, wfrag, q_bias, v_bias, ls,
                                     qh, kh, vhT);
  attn_kernel<<<1728, 256, 0, stream>>>(qh, kh, vhT, Rtab, ah);
  proj_mfma<<<1728, 256, 0, stream>>>(ah, ph, proj_b, out);
}